// Round 9
// baseline (130.440 us; speedup 1.0000x reference)
//
#include <hip/hip_runtime.h>
#include <hip/hip_bf16.h>
#include <stdint.h>

#define TT 2048
#define CC 1024
#define NH 16
#define HD 64
#define QKVN 3072

typedef __attribute__((ext_vector_type(8))) short short8;
typedef __attribute__((ext_vector_type(4))) float floatx4;
typedef __attribute__((ext_vector_type(4))) unsigned short ushortx4;

typedef const __attribute__((address_space(1))) void gas_void;
typedef __attribute__((address_space(3))) void las_void;

__device__ __forceinline__ void gload16(const void* g, void* l) {
  __builtin_amdgcn_global_load_lds((gas_void*)g, (las_void*)l, 16, 0, 0);
}

__device__ __forceinline__ unsigned short f2bf(float f) {
  union { float f; uint32_t u; } v; v.f = f;
  uint32_t u = v.u;
  uint32_t r = (u + 0x7fffu + ((u >> 16) & 1u)) >> 16;
  return (unsigned short)r;
}

__device__ __forceinline__ float fexp2(float x) {
#if __has_builtin(__builtin_amdgcn_exp2f)
  return __builtin_amdgcn_exp2f(x);
#else
  return exp2f(x);
#endif
}

#define QSCALE 0.18033688011112042f  // (1/8)*log2(e), folded into Wq/bq

// kv permutation within a 64-block: chunk c'=4kk+g holds runs [kA..kA+3, kA+8..kA+11]
__device__ __forceinline__ int perm64(int t) {
  const int kk = t >> 5, r5 = t & 31;
  const int g = ((r5 >> 3) & 2) | ((r5 >> 2) & 1);
  const int slot = (r5 & 3) | ((r5 >> 1) & 4);
  return kk * 32 + g * 8 + slot;
}

// ---------------- fused f32 -> bf16 conversion; Wq pre-scaled by QSCALE ----------------
__global__ __launch_bounds__(256) void cvt_fused(const float* __restrict__ x,
                                                 const float* __restrict__ wq,
                                                 const float* __restrict__ wk,
                                                 const float* __restrict__ wv,
                                                 const float* __restrict__ wp,
                                                 unsigned short* __restrict__ xb,
                                                 unsigned short* __restrict__ wqkvb,
                                                 unsigned short* __restrict__ wpb) {
  const int i = blockIdx.x * blockDim.x + threadIdx.x;  // f4 index, total 2097152
  if (i < 1048576) {            // x: 4096x1024
    const float4 v = reinterpret_cast<const float4*>(x)[i];
    ushortx4 o; o[0] = f2bf(v.x); o[1] = f2bf(v.y); o[2] = f2bf(v.z); o[3] = f2bf(v.w);
    reinterpret_cast<ushortx4*>(xb)[i] = o;
    return;
  }
  const int j = i - 1048576;     // 0..1048575 over 4 weight matrices
  const int seg = j >> 18;       // 262144 f4 per weight
  const int idx = j & 262143;
  const float* src = (seg == 0) ? wq : (seg == 1) ? wk : (seg == 2) ? wv : wp;
  const float sc = (seg == 0) ? QSCALE : 1.0f;
  const float4 v = reinterpret_cast<const float4*>(src)[idx];
  ushortx4 o;
  o[0] = f2bf(v.x * sc); o[1] = f2bf(v.y * sc); o[2] = f2bf(v.z * sc); o[3] = f2bf(v.w * sc);
  if (seg < 3)
    reinterpret_cast<ushortx4*>(wqkvb)[j] = o;       // q,k,v contiguous thirds
  else
    reinterpret_cast<ushortx4*>(wpb)[idx] = o;
}

// ---------------- QKV GEMM: 256x256 tile, 8 waves, counted-vmcnt 2-deep pipeline ------
__global__ __launch_bounds__(512) void gemm_qkv(const unsigned short* __restrict__ A,
                                                const unsigned short* __restrict__ W,
                                                const float* __restrict__ b0,
                                                const float* __restrict__ b1,
                                                const float* __restrict__ b2,
                                                unsigned short* __restrict__ out,
                                                unsigned short* __restrict__ Vt) {
  __shared__ unsigned short lsA[2][256 * 64];
  __shared__ unsigned short lsB[2][256 * 64];
  const int tid = threadIdx.x;
  const int wave = tid >> 6, lane = tid & 63;
  const int g = lane >> 4, c16 = lane & 15;
  const int m0 = blockIdx.y * 256, n0 = blockIdx.x * 256;
  const int wm = (wave >> 2) * 128, wn = (wave & 3) * 64;

  floatx4 acc[8][4];
#pragma unroll
  for (int i = 0; i < 8; ++i)
#pragma unroll
    for (int j = 0; j < 4; ++j) acc[i][j] = (floatx4){0.f, 0.f, 0.f, 0.f};

  const int srow = lane >> 3, sj = lane & 7;

  auto stageT = [&](int buf, int kt) {
#pragma unroll
    for (int rho = 0; rho < 4; ++rho) {
      const int kb = wave * 4 + rho;            // 0..31 (1 KB groups)
      const int r = kb * 8 + srow;              // tile row 0..255
      const int gj = (sj ^ (r & 7)) << 3;       // pre-swizzled source column
      gload16(A + (size_t)(m0 + r) * CC + kt + gj, (char*)lsA[buf] + kb * 1024);
      gload16(W + (size_t)(n0 + r) * CC + kt + gj, (char*)lsB[buf] + kb * 1024);
    }
  };

  stageT(0, 0);
  stageT(1, 64);
  asm volatile("s_waitcnt vmcnt(8)" ::: "memory");   // tile0 landed; tile1 in flight
  __builtin_amdgcn_s_barrier();

#pragma unroll 2
  for (int t = 0; t < 16; ++t) {
    const int buf = t & 1;
    const char* la = (const char*)lsA[buf];
    const char* lb = (const char*)lsB[buf];
#pragma unroll
    for (int p = 0; p < 4; ++p) {
      const int ih = (p >> 1) * 4;   // i-quadrant base
      const int jh = (p & 1) * 2;    // j-quadrant base
      short8 af[4][2], bfr[2][2];
#pragma unroll
      for (int i = 0; i < 4; ++i) {
        const int ra = wm + (ih + i) * 16 + c16;
#pragma unroll
        for (int kk = 0; kk < 2; ++kk) {
          const int ca = (kk * 4 + g) ^ (ra & 7);
          af[i][kk] = *reinterpret_cast<const short8*>(la + ra * 128 + (ca << 4));
        }
      }
#pragma unroll
      for (int j = 0; j < 2; ++j) {
        const int rb = wn + (jh + j) * 16 + c16;
#pragma unroll
        for (int kk = 0; kk < 2; ++kk) {
          const int cb = (kk * 4 + g) ^ (rb & 7);
          bfr[j][kk] = *reinterpret_cast<const short8*>(lb + rb * 128 + (cb << 4));
        }
      }
      asm volatile("s_waitcnt lgkmcnt(0)" ::: "memory");
      __builtin_amdgcn_sched_barrier(0);
      __builtin_amdgcn_s_setprio(1);
#pragma unroll
      for (int kk = 0; kk < 2; ++kk)
#pragma unroll
        for (int i = 0; i < 4; ++i)
#pragma unroll
          for (int j = 0; j < 2; ++j)
            acc[ih + i][jh + j] = __builtin_amdgcn_mfma_f32_16x16x32_bf16(
                af[i][kk], bfr[j][kk], acc[ih + i][jh + j], 0, 0, 0);
      __builtin_amdgcn_s_setprio(0);
    }
    if (t < 15) {
      __builtin_amdgcn_s_barrier();                       // all done reading buf
      if (t < 14) {
        stageT(buf, (t + 2) * 64);                        // refill just-freed buf
        asm volatile("s_waitcnt vmcnt(8)" ::: "memory");  // t+1 certified
      } else {
        asm volatile("s_waitcnt vmcnt(0)" ::: "memory");  // tail: t15 certified
      }
      __builtin_amdgcn_s_barrier();
    }
  }

  // epilogue
  const int rgrp = g * 4;
  const float* bias = (n0 < 1024) ? b0 : (n0 < 2048 ? b1 : b2);
  const float bsc = (n0 < 1024) ? QSCALE : 1.0f;

  if (n0 >= 2048) {
#pragma unroll
    for (int i = 0; i < 8; ++i) {
      const int tk0 = m0 + wm + i * 16 + rgrp;        // 4-aligned token base
      const int bb = tk0 >> 11;
      const int tw = tk0 & 2047;
      const int tpos = (tw & ~63) + perm64(tw & 63);
#pragma unroll
      for (int j = 0; j < 4; ++j) {
        const int vdim = n0 - 2048 + wn + j * 16 + c16;
        const int h = vdim >> 6, d = vdim & 63;
        const float bv = bias[vdim];
        ushortx4 ov;
#pragma unroll
        for (int r = 0; r < 4; ++r) ov[r] = f2bf(acc[i][j][r] + bv);
        *reinterpret_cast<ushortx4*>(
            &Vt[((size_t)((bb * NH + h) * HD + d)) * TT + tpos]) = ov;
      }
    }
    return;
  }

#pragma unroll
  for (int i = 0; i < 8; ++i) {
    const int gm0 = m0 + wm + i * 16 + rgrp;
#pragma unroll
    for (int j = 0; j < 4; ++j) {
      const int gn = n0 + wn + j * 16 + c16;
      const float bv = bias[gn & 1023] * bsc;
#pragma unroll
      for (int r = 0; r < 4; ++r)
        out[(size_t)(gm0 + r) * QKVN + gn] = f2bf(acc[i][j][r] + bv);
    }
  }
}

// ---------------- proj GEMM: 128x128 tile, counted-vmcnt 2-deep (grid 256) ------------
__global__ __launch_bounds__(256) void gemm_proj(const unsigned short* __restrict__ A,
                                                 const unsigned short* __restrict__ W,
                                                 const float* __restrict__ bias,
                                                 float* __restrict__ outv) {
  __shared__ unsigned short lsA[2][128 * 64];
  __shared__ unsigned short lsB[2][128 * 64];
  const int tid = threadIdx.x;
  const int wave = tid >> 6, lane = tid & 63;
  const int m0 = blockIdx.y * 128, n0 = blockIdx.x * 128;
  const int wm = (wave >> 1) * 64, wn = (wave & 1) * 64;
  const int K = CC, N = CC;

  floatx4 acc[4][4];
#pragma unroll
  for (int i = 0; i < 4; ++i)
#pragma unroll
    for (int j = 0; j < 4; ++j)
      acc[i][j] = (floatx4){0.f, 0.f, 0.f, 0.f};

  const int sr = lane >> 3;
  const int sj = lane & 7;

  auto stageT = [&](int buf, int kt) {
#pragma unroll
    for (int t = 0; t < 4; ++t) {
      const int g4 = wave * 4 + t;
      const int r = g4 * 8 + sr;
      const int gj = (sj ^ (r & 7)) << 3;
      gload16(A + (size_t)(m0 + r) * K + kt + gj, (char*)lsA[buf] + g4 * 1024);
      gload16(W + (size_t)(n0 + r) * K + kt + gj, (char*)lsB[buf] + g4 * 1024);
    }
  };

  stageT(0, 0);
  stageT(1, 64);
  asm volatile("s_waitcnt vmcnt(8)" ::: "memory");
  __builtin_amdgcn_s_barrier();

#pragma unroll 2
  for (int t = 0; t < 16; ++t) {
    const int buf = t & 1;
    const char* la = (const char*)lsA[buf];
    const char* lb = (const char*)lsB[buf];
    short8 af[4][2], bfr[4][2];
#pragma unroll
    for (int i = 0; i < 4; ++i) {
      const int ra = wm + i * 16 + (lane & 15);
      const int rb = wn + i * 16 + (lane & 15);
#pragma unroll
      for (int kk = 0; kk < 2; ++kk) {
        const int ca = (kk * 4 + (lane >> 4)) ^ (ra & 7);
        const int cb = (kk * 4 + (lane >> 4)) ^ (rb & 7);
        af[i][kk] = *reinterpret_cast<const short8*>(la + ra * 128 + (ca << 4));
        bfr[i][kk] = *reinterpret_cast<const short8*>(lb + rb * 128 + (cb << 4));
      }
    }
    asm volatile("s_waitcnt lgkmcnt(0)" ::: "memory");
    __builtin_amdgcn_sched_barrier(0);
    __builtin_amdgcn_s_setprio(1);
#pragma unroll
    for (int kk = 0; kk < 2; ++kk)
#pragma unroll
      for (int i = 0; i < 4; ++i)
#pragma unroll
        for (int j = 0; j < 4; ++j)
          acc[i][j] = __builtin_amdgcn_mfma_f32_16x16x32_bf16(af[i][kk], bfr[j][kk],
                                                              acc[i][j], 0, 0, 0);
    __builtin_amdgcn_s_setprio(0);
    if (t < 15) {
      __builtin_amdgcn_s_barrier();
      if (t < 14) {
        stageT(buf, (t + 2) * 64);
        asm volatile("s_waitcnt vmcnt(8)" ::: "memory");
      } else {
        asm volatile("s_waitcnt vmcnt(0)" ::: "memory");
      }
      __builtin_amdgcn_s_barrier();
    }
  }

  const int col = lane & 15;
  const int rgrp = (lane >> 4) * 4;
#pragma unroll
  for (int i = 0; i < 4; ++i) {
    const int gm0 = m0 + wm + i * 16 + rgrp;
#pragma unroll
    for (int j = 0; j < 4; ++j) {
      const int gn = n0 + wn + j * 16 + col;
      const float bv = bias[gn];
#pragma unroll
      for (int r = 0; r < 4; ++r)
        outv[(size_t)(gm0 + r) * N + gn] = acc[i][j][r] + bv;
    }
  }
}

// ---------------- Flash attention: T15 double-pipeline (QKT(t+1) || softmax(t)) -------
// Grid (B*H, T/64): bh-on-x for XCD L2 locality. 4 waves; wave owns 16 q rows.
// Q pre-scaled by (1/8)log2e -> S log2-domain, P=2^S bounded, no running max.
// K staged 2 tiles ahead, V 1 ahead; per iter: stage -> vmcnt(4)+barrier ->
// snext=QKT(t+1) [MFMA] || exp/pack(scur) [VALU] -> PV(t) [MFMA] -> barrier.
__global__ __launch_bounds__(256) void attn_fwd(const unsigned short* __restrict__ QKV,
                                                const unsigned short* __restrict__ Vt,
                                                unsigned short* __restrict__ Ob) {
  __shared__ unsigned short lsK[2][64 * 64];
  __shared__ unsigned short lsV[2][64 * 64];
  const int tid = threadIdx.x;
  const int wave = tid >> 6, lane = tid & 63;
  const int g = lane >> 4;
  const int c16 = lane & 15;
  const int bh = blockIdx.x;
  const int b = bh >> 4, h = bh & 15;
  const int q0 = blockIdx.y * 64 + wave * 16;

  short8 qf[2];
  {
    const unsigned short* qp =
        QKV + (size_t)(b * TT + q0 + c16) * QKVN + h * HD + g * 8;
    qf[0] = *reinterpret_cast<const short8*>(qp);
    qf[1] = *reinterpret_cast<const short8*>(qp + 32);
  }

  short8 ones;
#pragma unroll
  for (int i = 0; i < 8; ++i) ones[i] = (short)0x3F80;  // bf16 1.0

  floatx4 o[4];
#pragma unroll
  for (int f = 0; f < 4; ++f) o[f] = (floatx4){0.f, 0.f, 0.f, 0.f};
  floatx4 lacc = (floatx4){0.f, 0.f, 0.f, 0.f};

  const int sr = lane >> 3, sj = lane & 7;

  auto stageK = [&](int buf, int kt) {
#pragma unroll
    for (int t = 0; t < 2; ++t) {
      const int g8 = wave * 2 + t;
      const int r = g8 * 8 + sr;
      const int gj = (sj ^ (r & 7)) << 3;
      gload16(QKV + (size_t)(b * TT + kt + r) * QKVN + CC + h * HD + gj,
              (char*)lsK[buf] + g8 * 1024);
    }
  };
  auto stageV = [&](int buf, int kt) {
#pragma unroll
    for (int t = 0; t < 2; ++t) {
      const int g8 = wave * 2 + t;
      const int r = g8 * 8 + sr;
      const int gj = (sj ^ (r & 7)) << 3;
      gload16(Vt + ((size_t)bh * HD + r) * TT + kt + gj, (char*)lsV[buf] + g8 * 1024);
    }
  };

  // S^T = K * Q^T (log2 domain)
  auto qkt = [&](floatx4* s, const unsigned short* lk) {
#pragma unroll
    for (int cb = 0; cb < 4; ++cb) s[cb] = (floatx4){0.f, 0.f, 0.f, 0.f};
    __builtin_amdgcn_s_setprio(1);
#pragma unroll
    for (int kk = 0; kk < 2; ++kk) {
#pragma unroll
      for (int cb = 0; cb < 4; ++cb) {
        const int rk = cb * 16 + c16;
        const int ck = (kk * 4 + g) ^ (rk & 7);
        const short8 kf =
            *reinterpret_cast<const short8*>((const char*)lk + rk * 128 + (ck << 4));
        s[cb] = __builtin_amdgcn_mfma_f32_16x16x32_bf16(kf, qf[kk], s[cb], 0, 0, 0);
      }
    }
    __builtin_amdgcn_s_setprio(0);
  };

  // P = 2^S, pack, O^T += V^T P^T, l += ones * P^T
  auto softpv = [&](floatx4* s, const unsigned short* lv) {
    unsigned int w[4][2];
#pragma unroll
    for (int cb = 0; cb < 4; ++cb) {
#pragma unroll
      for (int r = 0; r < 4; ++r) s[cb][r] = fexp2(s[cb][r]);
      asm("v_cvt_pk_bf16_f32 %0, %1, %2"
          : "=v"(w[cb][0]) : "v"(s[cb][0]), "v"(s[cb][1]));
      asm("v_cvt_pk_bf16_f32 %0, %1, %2"
          : "=v"(w[cb][1]) : "v"(s[cb][2]), "v"(s[cb][3]));
    }
#pragma unroll
    for (int kk = 0; kk < 2; ++kk) {
      unsigned int pa0 = w[2 * kk][0], pb0 = w[2 * kk + 1][0];
      unsigned int pa1 = w[2 * kk][1], pb1 = w[2 * kk + 1][1];
      asm("v_permlane32_swap_b32 %0, %1" : "+v"(pa0), "+v"(pb0));
      asm("v_permlane32_swap_b32 %0, %1" : "+v"(pa1), "+v"(pb1));
      union { unsigned int u[4]; short8 v; } pk;
      pk.u[0] = pa0; pk.u[1] = pa1; pk.u[2] = pb0; pk.u[3] = pb1;
      const short8 pbv = pk.v;
      __builtin_amdgcn_s_setprio(1);
#pragma unroll
      for (int f = 0; f < 4; ++f) {
        const int rv = f * 16 + c16;
        const int cv = (4 * kk + g) ^ (rv & 7);
        const short8 vf =
            *reinterpret_cast<const short8*>((const char*)lv + rv * 128 + (cv << 4));
        o[f] = __builtin_amdgcn_mfma_f32_16x16x32_bf16(vf, pbv, o[f], 0, 0, 0);
      }
      lacc = __builtin_amdgcn_mfma_f32_16x16x32_bf16(ones, pbv, lacc, 0, 0, 0);
      __builtin_amdgcn_s_setprio(0);
    }
  };

  // prologue: K(0),V(0),K(1) staged; full drain; S(0)
  stageK(0, 0);
  stageV(0, 0);
  stageK(1, 64);
  asm volatile("s_waitcnt vmcnt(0)" ::: "memory");
  __builtin_amdgcn_s_barrier();

  floatx4 scur[4];
  qkt(scur, (const unsigned short*)lsK[0]);
  __builtin_amdgcn_s_barrier();   // all waves done with prologue read of lsK[0]

#pragma unroll 2
  for (int it = 0; it < TT / 64; ++it) {
    const int kb = it & 1;
    // clamped (uniform) staging: K 2 ahead into lsK[kb], V 1 ahead into lsV[kb^1]
    const int ktK = (it + 2 < TT / 64 ? it + 2 : TT / 64 - 1) * 64;
    const int ktV = (it + 1 < TT / 64 ? it + 1 : TT / 64 - 1) * 64;
    stageK(kb, ktK);
    stageV(kb ^ 1, ktV);
    asm volatile("s_waitcnt vmcnt(4)" ::: "memory");   // prev iter's batch landed
    __builtin_amdgcn_s_barrier();
    floatx4 snext[4];
    if (it < TT / 64 - 1) qkt(snext, (const unsigned short*)lsK[kb ^ 1]);  // MFMA
    softpv(scur, (const unsigned short*)lsV[kb]);      // VALU || above, then PV MFMA
    __builtin_amdgcn_s_barrier();                      // all done reading this iter's bufs
    if (it < TT / 64 - 1) {
#pragma unroll
      for (int cb = 0; cb < 4; ++cb) scur[cb] = snext[cb];
    }
  }

  // epilogue: normalize, vectorized 8B stores
  {
    const float inv = 1.0f / lacc[0];
    const size_t gm = (size_t)(b * TT + q0 + c16) * CC;
#pragma unroll
    for (int f = 0; f < 4; ++f) {
      ushortx4 ov;
#pragma unroll
      for (int r = 0; r < 4; ++r) ov[r] = f2bf(o[f][r] * inv);
      *reinterpret_cast<ushortx4*>(&Ob[gm + h * HD + f * 16 + 4 * g]) = ov;
    }
  }
}

extern "C" void kernel_launch(void* const* d_in, const int* in_sizes, int n_in,
                              void* d_out, int out_size, void* d_ws, size_t ws_size,
                              hipStream_t stream) {
  (void)in_sizes; (void)n_in; (void)out_size; (void)ws_size;
  const float* x  = (const float*)d_in[0];
  const float* Wk = (const float*)d_in[1];
  const float* bk = (const float*)d_in[2];
  const float* Wq = (const float*)d_in[3];
  const float* bq = (const float*)d_in[4];
  const float* Wv = (const float*)d_in[5];
  const float* bv = (const float*)d_in[6];
  const float* Wp = (const float*)d_in[7];
  const float* bp = (const float*)d_in[8];
  float* out = (float*)d_out;

  char* ws = (char*)d_ws;
  const size_t MB = 1u << 20;
  unsigned short* xb    = (unsigned short*)(ws);            // 8 MB [4096][1024]
  unsigned short* Wqkvb = (unsigned short*)(ws + 8 * MB);   // 6 MB [3072][1024] (q,k,v)
  unsigned short* Wpb   = (unsigned short*)(ws + 14 * MB);  // 2 MB
  unsigned short* QKVb  = (unsigned short*)(ws + 16 * MB);  // 24 MB [4096][3072] (V third unused)
  unsigned short* Vtb   = (unsigned short*)(ws + 40 * MB);  // 8 MB [32][64][2048] permuted
  unsigned short* Ab    = (unsigned short*)(ws + 48 * MB);  // 8 MB [4096][1024]

  const int M = 2 * TT;  // 4096

  cvt_fused<<<8192, 256, 0, stream>>>(x, Wq, Wk, Wv, Wp, xb, Wqkvb, Wpb);

  // fused QKV GEMM (256^2 counted-vmcnt); V third written directly to permuted Vt
  gemm_qkv<<<dim3(QKVN / 256, M / 256), 512, 0, stream>>>(xb, Wqkvb, bq, bk, bv,
                                                          QKVb, Vtb);

  // bh on blockIdx.x: all q-chunks of one bh share an XCD -> K/V L2 locality
  attn_fwd<<<dim3(2 * NH, TT / 64), 256, 0, stream>>>(QKVb, Vtb, Ab);

  gemm_proj<<<dim3(CC / 128, M / 128), 256, 0, stream>>>(Ab, Wpb, bp, out);
}

// Round 10
// 119.759 us; speedup vs baseline: 1.0892x; 1.0892x over previous
//
#include <hip/hip_runtime.h>
#include <hip/hip_bf16.h>
#include <stdint.h>

#define TT 2048
#define CC 1024
#define NH 16
#define HD 64
#define QKVN 3072

typedef __attribute__((ext_vector_type(8))) short short8;
typedef __attribute__((ext_vector_type(4))) float floatx4;
typedef __attribute__((ext_vector_type(4))) unsigned short ushortx4;

typedef const __attribute__((address_space(1))) void gas_void;
typedef __attribute__((address_space(3))) void las_void;

__device__ __forceinline__ void gload16(const void* g, void* l) {
  __builtin_amdgcn_global_load_lds((gas_void*)g, (las_void*)l, 16, 0, 0);
}

__device__ __forceinline__ unsigned short f2bf(float f) {
  union { float f; uint32_t u; } v; v.f = f;
  uint32_t u = v.u;
  uint32_t r = (u + 0x7fffu + ((u >> 16) & 1u)) >> 16;
  return (unsigned short)r;
}

__device__ __forceinline__ float fexp2(float x) {
#if __has_builtin(__builtin_amdgcn_exp2f)
  return __builtin_amdgcn_exp2f(x);
#else
  return exp2f(x);
#endif
}

#define QSCALE 0.18033688011112042f  // (1/8)*log2(e), folded into Wq/bq

// kv permutation within a 64-block: chunk c'=4kk+g holds runs [kA..kA+3, kA+8..kA+11]
__device__ __forceinline__ int perm64(int t) {
  const int kk = t >> 5, r5 = t & 31;
  const int g = ((r5 >> 3) & 2) | ((r5 >> 2) & 1);
  const int slot = (r5 & 3) | ((r5 >> 1) & 4);
  return kk * 32 + g * 8 + slot;
}

// ---------------- fused f32 -> bf16 conversion; Wq pre-scaled by QSCALE ----------------
__global__ __launch_bounds__(256) void cvt_fused(const float* __restrict__ x,
                                                 const float* __restrict__ wq,
                                                 const float* __restrict__ wk,
                                                 const float* __restrict__ wv,
                                                 const float* __restrict__ wp,
                                                 unsigned short* __restrict__ xb,
                                                 unsigned short* __restrict__ wqkvb,
                                                 unsigned short* __restrict__ wpb) {
  const int i = blockIdx.x * blockDim.x + threadIdx.x;  // f4 index, total 2097152
  if (i < 1048576) {            // x: 4096x1024
    const float4 v = reinterpret_cast<const float4*>(x)[i];
    ushortx4 o; o[0] = f2bf(v.x); o[1] = f2bf(v.y); o[2] = f2bf(v.z); o[3] = f2bf(v.w);
    reinterpret_cast<ushortx4*>(xb)[i] = o;
    return;
  }
  const int j = i - 1048576;     // 0..1048575 over 4 weight matrices
  const int seg = j >> 18;       // 262144 f4 per weight
  const int idx = j & 262143;
  const float* src = (seg == 0) ? wq : (seg == 1) ? wk : (seg == 2) ? wv : wp;
  const float sc = (seg == 0) ? QSCALE : 1.0f;
  const float4 v = reinterpret_cast<const float4*>(src)[idx];
  ushortx4 o;
  o[0] = f2bf(v.x * sc); o[1] = f2bf(v.y * sc); o[2] = f2bf(v.z * sc); o[3] = f2bf(v.w * sc);
  if (seg < 3)
    reinterpret_cast<ushortx4*>(wqkvb)[j] = o;       // q,k,v contiguous thirds
  else
    reinterpret_cast<ushortx4*>(wpb)[idx] = o;
}

// ---------------- QKV GEMM: 256x192 tile -> grid 16x16 = 256 blocks = 1/CU -----------
// C[m][n] = sum_k A[m][k]*W[n][k] + bias; M=4096, N=3072, K=1024.
// 8 waves 2(M)x4(N); per-wave 128x48 out (acc 8x3). LDS 112 KB double-buffered,
// XOR-chunk swizzle. Counted-vmcnt 2-deep: compute(t) -> barrier -> stage(t+2) ->
// vmcnt(7) [t+1 certified, t+2 in flight] -> barrier. Never vmcnt(0) mid-loop.
// Epilogue routes per 16-wide fragment: V third -> permuted Vt, else -> QKV buffer.
__global__ __launch_bounds__(512) void gemm_qkv(const unsigned short* __restrict__ A,
                                                const unsigned short* __restrict__ W,
                                                const float* __restrict__ b0,
                                                const float* __restrict__ b1,
                                                const float* __restrict__ b2,
                                                unsigned short* __restrict__ out,
                                                unsigned short* __restrict__ Vt) {
  __shared__ unsigned short lsA[2][256 * 64];
  __shared__ unsigned short lsB[2][192 * 64];
  const int tid = threadIdx.x;
  const int wave = tid >> 6, lane = tid & 63;
  const int g = lane >> 4, c16 = lane & 15;
  const int m0 = blockIdx.y * 256, n0 = blockIdx.x * 192;
  const int wm = (wave >> 2) * 128, wn = (wave & 3) * 48;

  floatx4 acc[8][3];
#pragma unroll
  for (int i = 0; i < 8; ++i)
#pragma unroll
    for (int j = 0; j < 3; ++j) acc[i][j] = (floatx4){0.f, 0.f, 0.f, 0.f};

  const int srow = lane >> 3, sj = lane & 7;

  // stage one 256x64 A-tile (4 KB-groups/wave) + 192x64 B-tile (3/wave) = 7 gload16
  auto stageT = [&](int buf, int kt) {
#pragma unroll
    for (int rho = 0; rho < 4; ++rho) {
      const int kb = wave * 4 + rho;            // 0..31
      const int r = kb * 8 + srow;              // A row 0..255
      const int gj = (sj ^ (r & 7)) << 3;       // pre-swizzled source column
      gload16(A + (size_t)(m0 + r) * CC + kt + gj, (char*)lsA[buf] + kb * 1024);
    }
#pragma unroll
    for (int rho = 0; rho < 3; ++rho) {
      const int kb = wave * 3 + rho;            // 0..23
      const int r = kb * 8 + srow;              // B row 0..191
      const int gj = (sj ^ (r & 7)) << 3;
      gload16(W + (size_t)(n0 + r) * CC + kt + gj, (char*)lsB[buf] + kb * 1024);
    }
  };

  stageT(0, 0);
  stageT(1, 64);
  asm volatile("s_waitcnt vmcnt(7)" ::: "memory");   // tile0 landed; tile1 in flight
  __builtin_amdgcn_s_barrier();

#pragma unroll 2
  for (int t = 0; t < 16; ++t) {
    const int buf = t & 1;
    const char* la = (const char*)lsA[buf];
    const char* lb = (const char*)lsB[buf];
    short8 af[8][2], bfr[3][2];
#pragma unroll
    for (int i = 0; i < 8; ++i) {
      const int ra = wm + i * 16 + c16;
#pragma unroll
      for (int kk = 0; kk < 2; ++kk) {
        const int ca = (kk * 4 + g) ^ (ra & 7);
        af[i][kk] = *reinterpret_cast<const short8*>(la + ra * 128 + (ca << 4));
      }
    }
#pragma unroll
    for (int j = 0; j < 3; ++j) {
      const int rb = wn + j * 16 + c16;
#pragma unroll
      for (int kk = 0; kk < 2; ++kk) {
        const int cb = (kk * 4 + g) ^ (rb & 7);
        bfr[j][kk] = *reinterpret_cast<const short8*>(lb + rb * 128 + (cb << 4));
      }
    }
    asm volatile("s_waitcnt lgkmcnt(0)" ::: "memory");
    __builtin_amdgcn_sched_barrier(0);
    __builtin_amdgcn_s_setprio(1);
#pragma unroll
    for (int kk = 0; kk < 2; ++kk)
#pragma unroll
      for (int i = 0; i < 8; ++i)
#pragma unroll
        for (int j = 0; j < 3; ++j)
          acc[i][j] = __builtin_amdgcn_mfma_f32_16x16x32_bf16(af[i][kk], bfr[j][kk],
                                                              acc[i][j], 0, 0, 0);
    __builtin_amdgcn_s_setprio(0);
    if (t < 15) {
      __builtin_amdgcn_s_barrier();                       // all done reading buf
      if (t < 14) {
        stageT(buf, (t + 2) * 64);                        // refill just-freed buf
        asm volatile("s_waitcnt vmcnt(7)" ::: "memory");  // t+1 certified
      } else {
        asm volatile("s_waitcnt vmcnt(0)" ::: "memory");  // tail: t15 certified
      }
      __builtin_amdgcn_s_barrier();
    }
  }

  // epilogue: per-fragment segment routing (192-tiles straddle 1024 boundaries)
  const int rgrp = g * 4;
#pragma unroll
  for (int i = 0; i < 8; ++i) {
    const int tk0 = m0 + wm + i * 16 + rgrp;        // 4-aligned token base
    const int bb = tk0 >> 11;
    const int tw = tk0 & 2047;
    const int tpos = (tw & ~63) + perm64(tw & 63);
#pragma unroll
    for (int j = 0; j < 3; ++j) {
      const int gn = n0 + wn + j * 16 + c16;
      const int seg = gn >> 10;
      const float bv = ((seg == 0) ? b0 : (seg == 1) ? b1 : b2)[gn & 1023] *
                       ((seg == 0) ? QSCALE : 1.0f);
      if (gn >= 2048) {
        // V third -> Vt[bh][d][perm(t)], 4 consecutive tokens per ushortx4 store
        const int vdim = gn - 2048;
        const int h = vdim >> 6, d = vdim & 63;
        ushortx4 ov;
#pragma unroll
        for (int r = 0; r < 4; ++r) ov[r] = f2bf(acc[i][j][r] + bv);
        *reinterpret_cast<ushortx4*>(
            &Vt[((size_t)((bb * NH + h) * HD + d)) * TT + tpos]) = ov;
      } else {
#pragma unroll
        for (int r = 0; r < 4; ++r)
          out[(size_t)(tk0 + r) * QKVN + gn] = f2bf(acc[i][j][r] + bv);
      }
    }
  }
}

// ---------------- proj GEMM: 128x128 tile, counted-vmcnt 2-deep (grid 256) ------------
__global__ __launch_bounds__(256) void gemm_proj(const unsigned short* __restrict__ A,
                                                 const unsigned short* __restrict__ W,
                                                 const float* __restrict__ bias,
                                                 float* __restrict__ outv) {
  __shared__ unsigned short lsA[2][128 * 64];
  __shared__ unsigned short lsB[2][128 * 64];
  const int tid = threadIdx.x;
  const int wave = tid >> 6, lane = tid & 63;
  const int m0 = blockIdx.y * 128, n0 = blockIdx.x * 128;
  const int wm = (wave >> 1) * 64, wn = (wave & 1) * 64;
  const int K = CC, N = CC;

  floatx4 acc[4][4];
#pragma unroll
  for (int i = 0; i < 4; ++i)
#pragma unroll
    for (int j = 0; j < 4; ++j)
      acc[i][j] = (floatx4){0.f, 0.f, 0.f, 0.f};

  const int sr = lane >> 3;
  const int sj = lane & 7;

  auto stageT = [&](int buf, int kt) {
#pragma unroll
    for (int t = 0; t < 4; ++t) {
      const int g4 = wave * 4 + t;
      const int r = g4 * 8 + sr;
      const int gj = (sj ^ (r & 7)) << 3;
      gload16(A + (size_t)(m0 + r) * K + kt + gj, (char*)lsA[buf] + g4 * 1024);
      gload16(W + (size_t)(n0 + r) * K + kt + gj, (char*)lsB[buf] + g4 * 1024);
    }
  };

  stageT(0, 0);
  stageT(1, 64);
  asm volatile("s_waitcnt vmcnt(8)" ::: "memory");
  __builtin_amdgcn_s_barrier();

#pragma unroll 2
  for (int t = 0; t < 16; ++t) {
    const int buf = t & 1;
    const char* la = (const char*)lsA[buf];
    const char* lb = (const char*)lsB[buf];
    short8 af[4][2], bfr[4][2];
#pragma unroll
    for (int i = 0; i < 4; ++i) {
      const int ra = wm + i * 16 + (lane & 15);
      const int rb = wn + i * 16 + (lane & 15);
#pragma unroll
      for (int kk = 0; kk < 2; ++kk) {
        const int ca = (kk * 4 + (lane >> 4)) ^ (ra & 7);
        const int cb = (kk * 4 + (lane >> 4)) ^ (rb & 7);
        af[i][kk] = *reinterpret_cast<const short8*>(la + ra * 128 + (ca << 4));
        bfr[i][kk] = *reinterpret_cast<const short8*>(lb + rb * 128 + (cb << 4));
      }
    }
    asm volatile("s_waitcnt lgkmcnt(0)" ::: "memory");
    __builtin_amdgcn_sched_barrier(0);
    __builtin_amdgcn_s_setprio(1);
#pragma unroll
    for (int kk = 0; kk < 2; ++kk)
#pragma unroll
      for (int i = 0; i < 4; ++i)
#pragma unroll
        for (int j = 0; j < 4; ++j)
          acc[i][j] = __builtin_amdgcn_mfma_f32_16x16x32_bf16(af[i][kk], bfr[j][kk],
                                                              acc[i][j], 0, 0, 0);
    __builtin_amdgcn_s_setprio(0);
    if (t < 15) {
      __builtin_amdgcn_s_barrier();
      if (t < 14) {
        stageT(buf, (t + 2) * 64);
        asm volatile("s_waitcnt vmcnt(8)" ::: "memory");
      } else {
        asm volatile("s_waitcnt vmcnt(0)" ::: "memory");
      }
      __builtin_amdgcn_s_barrier();
    }
  }

  const int col = lane & 15;
  const int rgrp = (lane >> 4) * 4;
#pragma unroll
  for (int i = 0; i < 4; ++i) {
    const int gm0 = m0 + wm + i * 16 + rgrp;
#pragma unroll
    for (int j = 0; j < 4; ++j) {
      const int gn = n0 + wn + j * 16 + col;
      const float bv = bias[gn];
#pragma unroll
      for (int r = 0; r < 4; ++r)
        outv[(size_t)(gm0 + r) * N + gn] = acc[i][j][r] + bv;
    }
  }
}

// ---------------- Flash attention: m=0 softmax, counted-vmcnt pipeline (R8 version) ---
// Grid (B*H, T/64): blockIdx.x = bh so all 32 q-chunk blocks of one bh land on the
// same XCD -> K/V re-reads are L2 hits. 4 waves; wave owns 16 q rows. Q pre-scaled
// by (1/8)log2e -> S log2-domain, P=2^S bounded, no running max. l via mfma(ones,P).
__global__ __launch_bounds__(256) void attn_fwd(const unsigned short* __restrict__ QKV,
                                                const unsigned short* __restrict__ Vt,
                                                unsigned short* __restrict__ Ob) {
  __shared__ unsigned short lsK[2][64 * 64];
  __shared__ unsigned short lsV[2][64 * 64];
  const int tid = threadIdx.x;
  const int wave = tid >> 6, lane = tid & 63;
  const int g = lane >> 4;
  const int c16 = lane & 15;
  const int bh = blockIdx.x;
  const int b = bh >> 4, h = bh & 15;
  const int q0 = blockIdx.y * 64 + wave * 16;

  short8 qf[2];
  {
    const unsigned short* qp =
        QKV + (size_t)(b * TT + q0 + c16) * QKVN + h * HD + g * 8;
    qf[0] = *reinterpret_cast<const short8*>(qp);
    qf[1] = *reinterpret_cast<const short8*>(qp + 32);
  }

  short8 ones;
#pragma unroll
  for (int i = 0; i < 8; ++i) ones[i] = (short)0x3F80;  // bf16 1.0

  floatx4 o[4];
#pragma unroll
  for (int f = 0; f < 4; ++f) o[f] = (floatx4){0.f, 0.f, 0.f, 0.f};
  floatx4 lacc = (floatx4){0.f, 0.f, 0.f, 0.f};

  const int sr = lane >> 3, sj = lane & 7;

  auto stage = [&](int buf, int kt) {
#pragma unroll
    for (int t = 0; t < 2; ++t) {
      const int g8 = wave * 2 + t;
      const int r = g8 * 8 + sr;
      const int gj = (sj ^ (r & 7)) << 3;
      gload16(QKV + (size_t)(b * TT + kt + r) * QKVN + CC + h * HD + gj,
              (char*)lsK[buf] + g8 * 1024);
      gload16(Vt + ((size_t)bh * HD + r) * TT + kt + gj, (char*)lsV[buf] + g8 * 1024);
    }
  };

  auto compute = [&](const unsigned short* lk, const unsigned short* lv) {
    // S^T = K * Q^T  (log2 domain)
    floatx4 s[4];
#pragma unroll
    for (int cb = 0; cb < 4; ++cb) s[cb] = (floatx4){0.f, 0.f, 0.f, 0.f};
    __builtin_amdgcn_s_setprio(1);
#pragma unroll
    for (int kk = 0; kk < 2; ++kk) {
#pragma unroll
      for (int cb = 0; cb < 4; ++cb) {
        const int rk = cb * 16 + c16;
        const int ck = (kk * 4 + g) ^ (rk & 7);
        const short8 kf =
            *reinterpret_cast<const short8*>((const char*)lk + rk * 128 + (ck << 4));
        s[cb] = __builtin_amdgcn_mfma_f32_16x16x32_bf16(kf, qf[kk], s[cb], 0, 0, 0);
      }
    }
    __builtin_amdgcn_s_setprio(0);

    // P = 2^S and pack to bf16 pairs
    unsigned int w[4][2];
#pragma unroll
    for (int cb = 0; cb < 4; ++cb) {
#pragma unroll
      for (int r = 0; r < 4; ++r) s[cb][r] = fexp2(s[cb][r]);
      asm("v_cvt_pk_bf16_f32 %0, %1, %2"
          : "=v"(w[cb][0]) : "v"(s[cb][0]), "v"(s[cb][1]));
      asm("v_cvt_pk_bf16_f32 %0, %1, %2"
          : "=v"(w[cb][1]) : "v"(s[cb][2]), "v"(s[cb][3]));
    }

    // O^T += V^T * P^T ; l += ones * P^T (denominator on the matrix pipe)
#pragma unroll
    for (int kk = 0; kk < 2; ++kk) {
      unsigned int pa0 = w[2 * kk][0], pb0 = w[2 * kk + 1][0];
      unsigned int pa1 = w[2 * kk][1], pb1 = w[2 * kk + 1][1];
      asm("v_permlane32_swap_b32 %0, %1" : "+v"(pa0), "+v"(pb0));
      asm("v_permlane32_swap_b32 %0, %1" : "+v"(pa1), "+v"(pb1));
      union { unsigned int u[4]; short8 v; } pk;
      pk.u[0] = pa0; pk.u[1] = pa1; pk.u[2] = pb0; pk.u[3] = pb1;
      const short8 pbv = pk.v;
      __builtin_amdgcn_s_setprio(1);
#pragma unroll
      for (int f = 0; f < 4; ++f) {
        const int rv = f * 16 + c16;
        const int cv = (4 * kk + g) ^ (rv & 7);
        const short8 vf =
            *reinterpret_cast<const short8*>((const char*)lv + rv * 128 + (cv << 4));
        o[f] = __builtin_amdgcn_mfma_f32_16x16x32_bf16(vf, pbv, o[f], 0, 0, 0);
      }
      lacc = __builtin_amdgcn_mfma_f32_16x16x32_bf16(ones, pbv, lacc, 0, 0, 0);
      __builtin_amdgcn_s_setprio(0);
    }
  };

  stage(0, 0);

#pragma unroll 2
  for (int it = 0; it < TT / 64; ++it) {
    const int buf = it & 1;
    if (it < TT / 64 - 1) {
      stage(buf ^ 1, (it + 1) * 64);                      // prefetch stays in flight
      asm volatile("s_waitcnt vmcnt(4)" ::: "memory");    // only current tile landed
    } else {
      asm volatile("s_waitcnt vmcnt(0)" ::: "memory");
    }
    __builtin_amdgcn_s_barrier();                         // all waves: buf ready
    __builtin_amdgcn_sched_barrier(0);
    compute((const unsigned short*)lsK[buf], (const unsigned short*)lsV[buf]);
    __builtin_amdgcn_s_barrier();                         // all waves done reading buf
  }

  // epilogue: normalize, vectorized 8B stores
  {
    const float inv = 1.0f / lacc[0];
    const size_t gm = (size_t)(b * TT + q0 + c16) * CC;
#pragma unroll
    for (int f = 0; f < 4; ++f) {
      ushortx4 ov;
#pragma unroll
      for (int r = 0; r < 4; ++r) ov[r] = f2bf(o[f][r] * inv);
      *reinterpret_cast<ushortx4*>(&Ob[gm + h * HD + f * 16 + 4 * g]) = ov;
    }
  }
}

extern "C" void kernel_launch(void* const* d_in, const int* in_sizes, int n_in,
                              void* d_out, int out_size, void* d_ws, size_t ws_size,
                              hipStream_t stream) {
  (void)in_sizes; (void)n_in; (void)out_size; (void)ws_size;
  const float* x  = (const float*)d_in[0];
  const float* Wk = (const float*)d_in[1];
  const float* bk = (const float*)d_in[2];
  const float* Wq = (const float*)d_in[3];
  const float* bq = (const float*)d_in[4];
  const float* Wv = (const float*)d_in[5];
  const float* bv = (const float*)d_in[6];
  const float* Wp = (const float*)d_in[7];
  const float* bp = (const float*)d_in[8];
  float* out = (float*)d_out;

  char* ws = (char*)d_ws;
  const size_t MB = 1u << 20;
  unsigned short* xb    = (unsigned short*)(ws);            // 8 MB [4096][1024]
  unsigned short* Wqkvb = (unsigned short*)(ws + 8 * MB);   // 6 MB [3072][1024] (q,k,v)
  unsigned short* Wpb   = (unsigned short*)(ws + 14 * MB);  // 2 MB
  unsigned short* QKVb  = (unsigned short*)(ws + 16 * MB);  // 24 MB [4096][3072] (V third unused)
  unsigned short* Vtb   = (unsigned short*)(ws + 40 * MB);  // 8 MB [32][64][2048] permuted
  unsigned short* Ab    = (unsigned short*)(ws + 48 * MB);  // 8 MB [4096][1024]

  const int M = 2 * TT;  // 4096

  cvt_fused<<<8192, 256, 0, stream>>>(x, Wq, Wk, Wv, Wp, xb, Wqkvb, Wpb);

  // fused QKV GEMM (256x192, 256 blocks = 1/CU); V third -> permuted Vt
  gemm_qkv<<<dim3(QKVN / 192, M / 256), 512, 0, stream>>>(xb, Wqkvb, bq, bk, bv,
                                                          QKVb, Vtb);

  // bh on blockIdx.x: all q-chunks of one bh share an XCD -> K/V L2 locality
  attn_fwd<<<dim3(2 * NH, TT / 64), 256, 0, stream>>>(QKVb, Vtb, Ab);

  gemm_proj<<<dim3(CC / 128, M / 128), 256, 0, stream>>>(Ab, Wpb, bp, out);
}

// Round 11
// 117.556 us; speedup vs baseline: 1.1096x; 1.0187x over previous
//
#include <hip/hip_runtime.h>
#include <hip/hip_bf16.h>
#include <stdint.h>

#define TT 2048
#define CC 1024
#define NH 16
#define HD 64
#define QKVN 3072

typedef __attribute__((ext_vector_type(8))) short short8;
typedef __attribute__((ext_vector_type(4))) float floatx4;
typedef __attribute__((ext_vector_type(4))) unsigned short ushortx4;

typedef const __attribute__((address_space(1))) void gas_void;
typedef __attribute__((address_space(3))) void las_void;

__device__ __forceinline__ void gload16(const void* g, void* l) {
  __builtin_amdgcn_global_load_lds((gas_void*)g, (las_void*)l, 16, 0, 0);
}

__device__ __forceinline__ unsigned short f2bf(float f) {
  union { float f; uint32_t u; } v; v.f = f;
  uint32_t u = v.u;
  uint32_t r = (u + 0x7fffu + ((u >> 16) & 1u)) >> 16;
  return (unsigned short)r;
}

__device__ __forceinline__ float fexp2(float x) {
#if __has_builtin(__builtin_amdgcn_exp2f)
  return __builtin_amdgcn_exp2f(x);
#else
  return exp2f(x);
#endif
}

#define QSCALE 0.18033688011112042f  // (1/8)*log2(e), folded into Wq/bq

// kv permutation within a 64-block: chunk c'=4kk+g holds runs [kA..kA+3, kA+8..kA+11]
__device__ __forceinline__ int perm64(int t) {
  const int kk = t >> 5, r5 = t & 31;
  const int g = ((r5 >> 3) & 2) | ((r5 >> 2) & 1);
  const int slot = (r5 & 3) | ((r5 >> 1) & 4);
  return kk * 32 + g * 8 + slot;
}

// ---------------- fused f32 -> bf16 conversion; Wq pre-scaled by QSCALE ----------------
__global__ __launch_bounds__(256) void cvt_fused(const float* __restrict__ x,
                                                 const float* __restrict__ wq,
                                                 const float* __restrict__ wk,
                                                 const float* __restrict__ wv,
                                                 const float* __restrict__ wp,
                                                 unsigned short* __restrict__ xb,
                                                 unsigned short* __restrict__ wqkvb,
                                                 unsigned short* __restrict__ wpb) {
  const int i = blockIdx.x * blockDim.x + threadIdx.x;  // f4 index, total 2097152
  if (i < 1048576) {            // x: 4096x1024
    const float4 v = reinterpret_cast<const float4*>(x)[i];
    ushortx4 o; o[0] = f2bf(v.x); o[1] = f2bf(v.y); o[2] = f2bf(v.z); o[3] = f2bf(v.w);
    reinterpret_cast<ushortx4*>(xb)[i] = o;
    return;
  }
  const int j = i - 1048576;     // 0..1048575 over 4 weight matrices
  const int seg = j >> 18;       // 262144 f4 per weight
  const int idx = j & 262143;
  const float* src = (seg == 0) ? wq : (seg == 1) ? wk : (seg == 2) ? wv : wp;
  const float sc = (seg == 0) ? QSCALE : 1.0f;
  const float4 v = reinterpret_cast<const float4*>(src)[idx];
  ushortx4 o;
  o[0] = f2bf(v.x * sc); o[1] = f2bf(v.y * sc); o[2] = f2bf(v.z * sc); o[3] = f2bf(v.w * sc);
  if (seg < 3)
    reinterpret_cast<ushortx4*>(wqkvb)[j] = o;       // q,k,v contiguous thirds
  else
    reinterpret_cast<ushortx4*>(wpb)[idx] = o;
}

// ---------------- QKV GEMM: 256x192 tile -> grid 16x16 = 256 blocks = 1/CU -----------
__global__ __launch_bounds__(512) void gemm_qkv(const unsigned short* __restrict__ A,
                                                const unsigned short* __restrict__ W,
                                                const float* __restrict__ b0,
                                                const float* __restrict__ b1,
                                                const float* __restrict__ b2,
                                                unsigned short* __restrict__ out,
                                                unsigned short* __restrict__ Vt) {
  __shared__ unsigned short lsA[2][256 * 64];
  __shared__ unsigned short lsB[2][192 * 64];
  const int tid = threadIdx.x;
  const int wave = tid >> 6, lane = tid & 63;
  const int g = lane >> 4, c16 = lane & 15;
  const int m0 = blockIdx.y * 256, n0 = blockIdx.x * 192;
  const int wm = (wave >> 2) * 128, wn = (wave & 3) * 48;

  floatx4 acc[8][3];
#pragma unroll
  for (int i = 0; i < 8; ++i)
#pragma unroll
    for (int j = 0; j < 3; ++j) acc[i][j] = (floatx4){0.f, 0.f, 0.f, 0.f};

  const int srow = lane >> 3, sj = lane & 7;

  auto stageT = [&](int buf, int kt) {
#pragma unroll
    for (int rho = 0; rho < 4; ++rho) {
      const int kb = wave * 4 + rho;            // 0..31
      const int r = kb * 8 + srow;              // A row 0..255
      const int gj = (sj ^ (r & 7)) << 3;       // pre-swizzled source column
      gload16(A + (size_t)(m0 + r) * CC + kt + gj, (char*)lsA[buf] + kb * 1024);
    }
#pragma unroll
    for (int rho = 0; rho < 3; ++rho) {
      const int kb = wave * 3 + rho;            // 0..23
      const int r = kb * 8 + srow;              // B row 0..191
      const int gj = (sj ^ (r & 7)) << 3;
      gload16(W + (size_t)(n0 + r) * CC + kt + gj, (char*)lsB[buf] + kb * 1024);
    }
  };

  stageT(0, 0);
  stageT(1, 64);
  asm volatile("s_waitcnt vmcnt(7)" ::: "memory");   // tile0 landed; tile1 in flight
  __builtin_amdgcn_s_barrier();

#pragma unroll 2
  for (int t = 0; t < 16; ++t) {
    const int buf = t & 1;
    const char* la = (const char*)lsA[buf];
    const char* lb = (const char*)lsB[buf];
    short8 af[8][2], bfr[3][2];
#pragma unroll
    for (int i = 0; i < 8; ++i) {
      const int ra = wm + i * 16 + c16;
#pragma unroll
      for (int kk = 0; kk < 2; ++kk) {
        const int ca = (kk * 4 + g) ^ (ra & 7);
        af[i][kk] = *reinterpret_cast<const short8*>(la + ra * 128 + (ca << 4));
      }
    }
#pragma unroll
    for (int j = 0; j < 3; ++j) {
      const int rb = wn + j * 16 + c16;
#pragma unroll
      for (int kk = 0; kk < 2; ++kk) {
        const int cb = (kk * 4 + g) ^ (rb & 7);
        bfr[j][kk] = *reinterpret_cast<const short8*>(lb + rb * 128 + (cb << 4));
      }
    }
    asm volatile("s_waitcnt lgkmcnt(0)" ::: "memory");
    __builtin_amdgcn_sched_barrier(0);
    __builtin_amdgcn_s_setprio(1);
#pragma unroll
    for (int kk = 0; kk < 2; ++kk)
#pragma unroll
      for (int i = 0; i < 8; ++i)
#pragma unroll
        for (int j = 0; j < 3; ++j)
          acc[i][j] = __builtin_amdgcn_mfma_f32_16x16x32_bf16(af[i][kk], bfr[j][kk],
                                                              acc[i][j], 0, 0, 0);
    __builtin_amdgcn_s_setprio(0);
    if (t < 15) {
      __builtin_amdgcn_s_barrier();                       // all done reading buf
      if (t < 14) {
        stageT(buf, (t + 2) * 64);                        // refill just-freed buf
        asm volatile("s_waitcnt vmcnt(7)" ::: "memory");  // t+1 certified
      } else {
        asm volatile("s_waitcnt vmcnt(0)" ::: "memory");  // tail: t15 certified
      }
      __builtin_amdgcn_s_barrier();
    }
  }

  // epilogue: per-fragment segment routing (192-tiles straddle 1024 boundaries)
  const int rgrp = g * 4;
#pragma unroll
  for (int i = 0; i < 8; ++i) {
    const int tk0 = m0 + wm + i * 16 + rgrp;        // 4-aligned token base
    const int bb = tk0 >> 11;
    const int tw = tk0 & 2047;
    const int tpos = (tw & ~63) + perm64(tw & 63);
#pragma unroll
    for (int j = 0; j < 3; ++j) {
      const int gn = n0 + wn + j * 16 + c16;
      const int seg = gn >> 10;
      const float bv = ((seg == 0) ? b0 : (seg == 1) ? b1 : b2)[gn & 1023] *
                       ((seg == 0) ? QSCALE : 1.0f);
      if (gn >= 2048) {
        const int vdim = gn - 2048;
        const int h = vdim >> 6, d = vdim & 63;
        ushortx4 ov;
#pragma unroll
        for (int r = 0; r < 4; ++r) ov[r] = f2bf(acc[i][j][r] + bv);
        *reinterpret_cast<ushortx4*>(
            &Vt[((size_t)((bb * NH + h) * HD + d)) * TT + tpos]) = ov;
      } else {
#pragma unroll
        for (int r = 0; r < 4; ++r)
          out[(size_t)(tk0 + r) * QKVN + gn] = f2bf(acc[i][j][r] + bv);
      }
    }
  }
}

// ---------------- proj GEMM: 128x128 tile, counted-vmcnt 2-deep (grid 256) ------------
__global__ __launch_bounds__(256) void gemm_proj(const unsigned short* __restrict__ A,
                                                 const unsigned short* __restrict__ W,
                                                 const float* __restrict__ bias,
                                                 float* __restrict__ outv) {
  __shared__ unsigned short lsA[2][128 * 64];
  __shared__ unsigned short lsB[2][128 * 64];
  const int tid = threadIdx.x;
  const int wave = tid >> 6, lane = tid & 63;
  const int m0 = blockIdx.y * 128, n0 = blockIdx.x * 128;
  const int wm = (wave >> 1) * 64, wn = (wave & 1) * 64;
  const int K = CC, N = CC;

  floatx4 acc[4][4];
#pragma unroll
  for (int i = 0; i < 4; ++i)
#pragma unroll
    for (int j = 0; j < 4; ++j)
      acc[i][j] = (floatx4){0.f, 0.f, 0.f, 0.f};

  const int sr = lane >> 3;
  const int sj = lane & 7;

  auto stageT = [&](int buf, int kt) {
#pragma unroll
    for (int t = 0; t < 4; ++t) {
      const int g4 = wave * 4 + t;
      const int r = g4 * 8 + sr;
      const int gj = (sj ^ (r & 7)) << 3;
      gload16(A + (size_t)(m0 + r) * K + kt + gj, (char*)lsA[buf] + g4 * 1024);
      gload16(W + (size_t)(n0 + r) * K + kt + gj, (char*)lsB[buf] + g4 * 1024);
    }
  };

  stageT(0, 0);
  stageT(1, 64);
  asm volatile("s_waitcnt vmcnt(8)" ::: "memory");
  __builtin_amdgcn_s_barrier();

#pragma unroll 2
  for (int t = 0; t < 16; ++t) {
    const int buf = t & 1;
    const char* la = (const char*)lsA[buf];
    const char* lb = (const char*)lsB[buf];
    short8 af[4][2], bfr[4][2];
#pragma unroll
    for (int i = 0; i < 4; ++i) {
      const int ra = wm + i * 16 + (lane & 15);
      const int rb = wn + i * 16 + (lane & 15);
#pragma unroll
      for (int kk = 0; kk < 2; ++kk) {
        const int ca = (kk * 4 + (lane >> 4)) ^ (ra & 7);
        const int cb = (kk * 4 + (lane >> 4)) ^ (rb & 7);
        af[i][kk] = *reinterpret_cast<const short8*>(la + ra * 128 + (ca << 4));
        bfr[i][kk] = *reinterpret_cast<const short8*>(lb + rb * 128 + (cb << 4));
      }
    }
    asm volatile("s_waitcnt lgkmcnt(0)" ::: "memory");
    __builtin_amdgcn_sched_barrier(0);
    __builtin_amdgcn_s_setprio(1);
#pragma unroll
    for (int kk = 0; kk < 2; ++kk)
#pragma unroll
      for (int i = 0; i < 4; ++i)
#pragma unroll
        for (int j = 0; j < 4; ++j)
          acc[i][j] = __builtin_amdgcn_mfma_f32_16x16x32_bf16(af[i][kk], bfr[j][kk],
                                                              acc[i][j], 0, 0, 0);
    __builtin_amdgcn_s_setprio(0);
    if (t < 15) {
      __builtin_amdgcn_s_barrier();
      if (t < 14) {
        stageT(buf, (t + 2) * 64);
        asm volatile("s_waitcnt vmcnt(8)" ::: "memory");
      } else {
        asm volatile("s_waitcnt vmcnt(0)" ::: "memory");
      }
      __builtin_amdgcn_s_barrier();
    }
  }

  const int col = lane & 15;
  const int rgrp = (lane >> 4) * 4;
#pragma unroll
  for (int i = 0; i < 4; ++i) {
    const int gm0 = m0 + wm + i * 16 + rgrp;
#pragma unroll
    for (int j = 0; j < 4; ++j) {
      const int gn = n0 + wn + j * 16 + col;
      const float bv = bias[gn];
#pragma unroll
      for (int r = 0; r < 4; ++r)
        outv[(size_t)(gm0 + r) * N + gn] = acc[i][j][r] + bv;
    }
  }
}

// ---------------- Flash attention: 2-wave blocks, 2 q-blocks/wave (LDS reuse x2) ------
// Grid (B*H, T/64), block=128. Wave owns 32 q rows as 2 q-blocks -> each K/V LDS
// fragment read serves 2x output (LDS traffic halved vs 16q/wave). 4 independent
// blocks/CU de-phase the MFMA/VALU bursts. bh on blockIdx.x pins each bh's K/V to
// one XCD L2. m=0 softmax (Q pre-scaled, log2 domain), l via mfma(ones,P).
__global__ __launch_bounds__(128) void attn_fwd(const unsigned short* __restrict__ QKV,
                                                const unsigned short* __restrict__ Vt,
                                                unsigned short* __restrict__ Ob) {
  __shared__ unsigned short lsK[2][64 * 64];
  __shared__ unsigned short lsV[2][64 * 64];
  const int tid = threadIdx.x;
  const int wave = tid >> 6, lane = tid & 63;
  const int g = lane >> 4;
  const int c16 = lane & 15;
  const int bh = blockIdx.x;
  const int b = bh >> 4, h = bh & 15;
  const int qw = blockIdx.y * 64 + wave * 32;

  short8 qf[2][2];
#pragma unroll
  for (int qb = 0; qb < 2; ++qb) {
    const unsigned short* qp =
        QKV + (size_t)(b * TT + qw + qb * 16 + c16) * QKVN + h * HD + g * 8;
    qf[qb][0] = *reinterpret_cast<const short8*>(qp);
    qf[qb][1] = *reinterpret_cast<const short8*>(qp + 32);
  }

  short8 ones;
#pragma unroll
  for (int i = 0; i < 8; ++i) ones[i] = (short)0x3F80;  // bf16 1.0

  floatx4 o[2][4];
#pragma unroll
  for (int qb = 0; qb < 2; ++qb)
#pragma unroll
    for (int f = 0; f < 4; ++f) o[qb][f] = (floatx4){0.f, 0.f, 0.f, 0.f};
  floatx4 lacc[2];
  lacc[0] = (floatx4){0.f, 0.f, 0.f, 0.f};
  lacc[1] = (floatx4){0.f, 0.f, 0.f, 0.f};

  const int sr = lane >> 3, sj = lane & 7;

  auto stage = [&](int buf, int kt) {
#pragma unroll
    for (int t = 0; t < 4; ++t) {
      const int g8 = wave * 4 + t;              // 0..7
      const int r = g8 * 8 + sr;                // 0..63
      const int gj = (sj ^ (r & 7)) << 3;
      gload16(QKV + (size_t)(b * TT + kt + r) * QKVN + CC + h * HD + gj,
              (char*)lsK[buf] + g8 * 1024);
      gload16(Vt + ((size_t)bh * HD + r) * TT + kt + gj, (char*)lsV[buf] + g8 * 1024);
    }
  };

  auto compute = [&](const unsigned short* lk, const unsigned short* lv) {
    // S^T = K * Q^T (log2 domain); kf shared across both q-blocks
    floatx4 s[2][4];
#pragma unroll
    for (int qb = 0; qb < 2; ++qb)
#pragma unroll
      for (int cb = 0; cb < 4; ++cb) s[qb][cb] = (floatx4){0.f, 0.f, 0.f, 0.f};
    __builtin_amdgcn_s_setprio(1);
#pragma unroll
    for (int kk = 0; kk < 2; ++kk) {
#pragma unroll
      for (int cb = 0; cb < 4; ++cb) {
        const int rk = cb * 16 + c16;
        const int ck = (kk * 4 + g) ^ (rk & 7);
        const short8 kf =
            *reinterpret_cast<const short8*>((const char*)lk + rk * 128 + (ck << 4));
        s[0][cb] = __builtin_amdgcn_mfma_f32_16x16x32_bf16(kf, qf[0][kk], s[0][cb], 0, 0, 0);
        s[1][cb] = __builtin_amdgcn_mfma_f32_16x16x32_bf16(kf, qf[1][kk], s[1][cb], 0, 0, 0);
      }
    }
    __builtin_amdgcn_s_setprio(0);

    // P = 2^S, pack to bf16 pairs
    unsigned int w[2][4][2];
#pragma unroll
    for (int qb = 0; qb < 2; ++qb) {
#pragma unroll
      for (int cb = 0; cb < 4; ++cb) {
#pragma unroll
        for (int r = 0; r < 4; ++r) s[qb][cb][r] = fexp2(s[qb][cb][r]);
        asm("v_cvt_pk_bf16_f32 %0, %1, %2"
            : "=v"(w[qb][cb][0]) : "v"(s[qb][cb][0]), "v"(s[qb][cb][1]));
        asm("v_cvt_pk_bf16_f32 %0, %1, %2"
            : "=v"(w[qb][cb][1]) : "v"(s[qb][cb][2]), "v"(s[qb][cb][3]));
      }
    }

    // O^T += V^T * P^T ; l += ones * P^T ; vf shared across both q-blocks
#pragma unroll
    for (int kk = 0; kk < 2; ++kk) {
      short8 pbv[2];
#pragma unroll
      for (int qb = 0; qb < 2; ++qb) {
        unsigned int pa0 = w[qb][2 * kk][0], pb0 = w[qb][2 * kk + 1][0];
        unsigned int pa1 = w[qb][2 * kk][1], pb1 = w[qb][2 * kk + 1][1];
        asm("v_permlane32_swap_b32 %0, %1" : "+v"(pa0), "+v"(pb0));
        asm("v_permlane32_swap_b32 %0, %1" : "+v"(pa1), "+v"(pb1));
        union { unsigned int u[4]; short8 v; } pk;
        pk.u[0] = pa0; pk.u[1] = pa1; pk.u[2] = pb0; pk.u[3] = pb1;
        pbv[qb] = pk.v;
      }
      __builtin_amdgcn_s_setprio(1);
#pragma unroll
      for (int f = 0; f < 4; ++f) {
        const int rv = f * 16 + c16;
        const int cv = (4 * kk + g) ^ (rv & 7);
        const short8 vf =
            *reinterpret_cast<const short8*>((const char*)lv + rv * 128 + (cv << 4));
        o[0][f] = __builtin_amdgcn_mfma_f32_16x16x32_bf16(vf, pbv[0], o[0][f], 0, 0, 0);
        o[1][f] = __builtin_amdgcn_mfma_f32_16x16x32_bf16(vf, pbv[1], o[1][f], 0, 0, 0);
      }
      lacc[0] = __builtin_amdgcn_mfma_f32_16x16x32_bf16(ones, pbv[0], lacc[0], 0, 0, 0);
      lacc[1] = __builtin_amdgcn_mfma_f32_16x16x32_bf16(ones, pbv[1], lacc[1], 0, 0, 0);
      __builtin_amdgcn_s_setprio(0);
    }
  };

  stage(0, 0);

#pragma unroll 2
  for (int it = 0; it < TT / 64; ++it) {
    const int buf = it & 1;
    if (it < TT / 64 - 1) {
      stage(buf ^ 1, (it + 1) * 64);                      // prefetch stays in flight
      asm volatile("s_waitcnt vmcnt(8)" ::: "memory");    // only current tile landed
    } else {
      asm volatile("s_waitcnt vmcnt(0)" ::: "memory");
    }
    __builtin_amdgcn_s_barrier();                         // both waves: buf ready
    __builtin_amdgcn_sched_barrier(0);
    compute((const unsigned short*)lsK[buf], (const unsigned short*)lsV[buf]);
    __builtin_amdgcn_s_barrier();                         // both waves done reading buf
  }

  // epilogue: normalize, vectorized 8B stores
#pragma unroll
  for (int qb = 0; qb < 2; ++qb) {
    const float inv = 1.0f / lacc[qb][0];
    const size_t gm = (size_t)(b * TT + qw + qb * 16 + c16) * CC;
#pragma unroll
    for (int f = 0; f < 4; ++f) {
      ushortx4 ov;
#pragma unroll
      for (int r = 0; r < 4; ++r) ov[r] = f2bf(o[qb][f][r] * inv);
      *reinterpret_cast<ushortx4*>(&Ob[gm + h * HD + f * 16 + 4 * g]) = ov;
    }
  }
}

extern "C" void kernel_launch(void* const* d_in, const int* in_sizes, int n_in,
                              void* d_out, int out_size, void* d_ws, size_t ws_size,
                              hipStream_t stream) {
  (void)in_sizes; (void)n_in; (void)out_size; (void)ws_size;
  const float* x  = (const float*)d_in[0];
  const float* Wk = (const float*)d_in[1];
  const float* bk = (const float*)d_in[2];
  const float* Wq = (const float*)d_in[3];
  const float* bq = (const float*)d_in[4];
  const float* Wv = (const float*)d_in[5];
  const float* bv = (const float*)d_in[6];
  const float* Wp = (const float*)d_in[7];
  const float* bp = (const float*)d_in[8];
  float* out = (float*)d_out;

  char* ws = (char*)d_ws;
  const size_t MB = 1u << 20;
  unsigned short* xb    = (unsigned short*)(ws);            // 8 MB [4096][1024]
  unsigned short* Wqkvb = (unsigned short*)(ws + 8 * MB);   // 6 MB [3072][1024] (q,k,v)
  unsigned short* Wpb   = (unsigned short*)(ws + 14 * MB);  // 2 MB
  unsigned short* QKVb  = (unsigned short*)(ws + 16 * MB);  // 24 MB [4096][3072] (V third unused)
  unsigned short* Vtb   = (unsigned short*)(ws + 40 * MB);  // 8 MB [32][64][2048] permuted
  unsigned short* Ab    = (unsigned short*)(ws + 48 * MB);  // 8 MB [4096][1024]

  const int M = 2 * TT;  // 4096

  cvt_fused<<<8192, 256, 0, stream>>>(x, Wq, Wk, Wv, Wp, xb, Wqkvb, Wpb);

  // fused QKV GEMM (256x192, 256 blocks = 1/CU); V third -> permuted Vt
  gemm_qkv<<<dim3(QKVN / 192, M / 256), 512, 0, stream>>>(xb, Wqkvb, bq, bk, bv,
                                                          QKVb, Vtb);

  // 2-wave blocks, qb=2: halved LDS fragment traffic, 4 independent blocks/CU
  attn_fwd<<<dim3(2 * NH, TT / 64), 128, 0, stream>>>(QKVb, Vtb, Ab);

  gemm_proj<<<dim3(CC / 128, M / 128), 256, 0, stream>>>(Ab, Wpb, bp, out);
}

// Round 12
// 117.328 us; speedup vs baseline: 1.1118x; 1.0019x over previous
//
#include <hip/hip_runtime.h>
#include <hip/hip_bf16.h>
#include <stdint.h>

#define TT 2048
#define CC 1024
#define NH 16
#define HD 64
#define QKVN 3072

typedef __attribute__((ext_vector_type(8))) short short8;
typedef __attribute__((ext_vector_type(4))) float floatx4;
typedef __attribute__((ext_vector_type(4))) unsigned short ushortx4;

typedef const __attribute__((address_space(1))) void gas_void;
typedef __attribute__((address_space(3))) void las_void;

__device__ __forceinline__ void gload16(const void* g, void* l) {
  __builtin_amdgcn_global_load_lds((gas_void*)g, (las_void*)l, 16, 0, 0);
}

__device__ __forceinline__ unsigned short f2bf(float f) {
  union { float f; uint32_t u; } v; v.f = f;
  uint32_t u = v.u;
  uint32_t r = (u + 0x7fffu + ((u >> 16) & 1u)) >> 16;
  return (unsigned short)r;
}

__device__ __forceinline__ float fexp2(float x) {
#if __has_builtin(__builtin_amdgcn_exp2f)
  return __builtin_amdgcn_exp2f(x);
#else
  return exp2f(x);
#endif
}

#define QSCALE 0.18033688011112042f  // (1/8)*log2(e), folded into Wq/bq

// kv permutation within a 64-block: chunk c'=4kk+g holds runs [kA..kA+3, kA+8..kA+11]
__device__ __forceinline__ int perm64(int t) {
  const int kk = t >> 5, r5 = t & 31;
  const int g = ((r5 >> 3) & 2) | ((r5 >> 2) & 1);
  const int slot = (r5 & 3) | ((r5 >> 1) & 4);
  return kk * 32 + g * 8 + slot;
}

// ---------------- fused f32 -> bf16 conversion; Wq pre-scaled by QSCALE ----------------
__global__ __launch_bounds__(256) void cvt_fused(const float* __restrict__ x,
                                                 const float* __restrict__ wq,
                                                 const float* __restrict__ wk,
                                                 const float* __restrict__ wv,
                                                 const float* __restrict__ wp,
                                                 unsigned short* __restrict__ xb,
                                                 unsigned short* __restrict__ wqkvb,
                                                 unsigned short* __restrict__ wpb) {
  const int i = blockIdx.x * blockDim.x + threadIdx.x;  // f4 index, total 2097152
  if (i < 1048576) {            // x: 4096x1024
    const float4 v = reinterpret_cast<const float4*>(x)[i];
    ushortx4 o; o[0] = f2bf(v.x); o[1] = f2bf(v.y); o[2] = f2bf(v.z); o[3] = f2bf(v.w);
    reinterpret_cast<ushortx4*>(xb)[i] = o;
    return;
  }
  const int j = i - 1048576;     // 0..1048575 over 4 weight matrices
  const int seg = j >> 18;       // 262144 f4 per weight
  const int idx = j & 262143;
  const float* src = (seg == 0) ? wq : (seg == 1) ? wk : (seg == 2) ? wv : wp;
  const float sc = (seg == 0) ? QSCALE : 1.0f;
  const float4 v = reinterpret_cast<const float4*>(src)[idx];
  ushortx4 o;
  o[0] = f2bf(v.x * sc); o[1] = f2bf(v.y * sc); o[2] = f2bf(v.z * sc); o[3] = f2bf(v.w * sc);
  if (seg < 3)
    reinterpret_cast<ushortx4*>(wqkvb)[j] = o;       // q,k,v contiguous thirds
  else
    reinterpret_cast<ushortx4*>(wpb)[idx] = o;
}

// ---------------- QKV GEMM: 256x192 tile, grid 256 linear w/ XCD-chunk swizzle --------
// vid=(orig&7)*32+orig>>3: each XCD owns 32 contiguous vids shaped 4(m)x8(n) ->
// per-XCD working set 2MB A + 3MB B ~ fits its 4MB L2 (A/B re-reads become L2 hits).
__global__ __launch_bounds__(512) void gemm_qkv(const unsigned short* __restrict__ A,
                                                const unsigned short* __restrict__ W,
                                                const float* __restrict__ b0,
                                                const float* __restrict__ b1,
                                                const float* __restrict__ b2,
                                                unsigned short* __restrict__ out,
                                                unsigned short* __restrict__ Vt) {
  __shared__ unsigned short lsA[2][256 * 64];
  __shared__ unsigned short lsB[2][192 * 64];
  const int tid = threadIdx.x;
  const int wave = tid >> 6, lane = tid & 63;
  const int g = lane >> 4, c16 = lane & 15;
  // XCD-aware swizzle (bijective: 256 blocks, 8 XCDs)
  const int orig = blockIdx.x;
  const int vid = (orig & 7) * 32 + (orig >> 3);
  const int chk = vid >> 5, wrm = vid & 31;
  const int m0 = ((chk & 3) * 4 + (wrm & 3)) * 256;
  const int n0 = ((chk >> 2) * 8 + (wrm >> 2)) * 192;
  const int wm = (wave >> 2) * 128, wn = (wave & 3) * 48;

  floatx4 acc[8][3];
#pragma unroll
  for (int i = 0; i < 8; ++i)
#pragma unroll
    for (int j = 0; j < 3; ++j) acc[i][j] = (floatx4){0.f, 0.f, 0.f, 0.f};

  const int srow = lane >> 3, sj = lane & 7;

  auto stageT = [&](int buf, int kt) {
#pragma unroll
    for (int rho = 0; rho < 4; ++rho) {
      const int kb = wave * 4 + rho;            // 0..31
      const int r = kb * 8 + srow;              // A row 0..255
      const int gj = (sj ^ (r & 7)) << 3;       // pre-swizzled source column
      gload16(A + (size_t)(m0 + r) * CC + kt + gj, (char*)lsA[buf] + kb * 1024);
    }
#pragma unroll
    for (int rho = 0; rho < 3; ++rho) {
      const int kb = wave * 3 + rho;            // 0..23
      const int r = kb * 8 + srow;              // B row 0..191
      const int gj = (sj ^ (r & 7)) << 3;
      gload16(W + (size_t)(n0 + r) * CC + kt + gj, (char*)lsB[buf] + kb * 1024);
    }
  };

  stageT(0, 0);
  stageT(1, 64);
  asm volatile("s_waitcnt vmcnt(7)" ::: "memory");   // tile0 landed; tile1 in flight
  __builtin_amdgcn_s_barrier();

#pragma unroll 2
  for (int t = 0; t < 16; ++t) {
    const int buf = t & 1;
    const char* la = (const char*)lsA[buf];
    const char* lb = (const char*)lsB[buf];
    short8 af[8][2], bfr[3][2];
#pragma unroll
    for (int i = 0; i < 8; ++i) {
      const int ra = wm + i * 16 + c16;
#pragma unroll
      for (int kk = 0; kk < 2; ++kk) {
        const int ca = (kk * 4 + g) ^ (ra & 7);
        af[i][kk] = *reinterpret_cast<const short8*>(la + ra * 128 + (ca << 4));
      }
    }
#pragma unroll
    for (int j = 0; j < 3; ++j) {
      const int rb = wn + j * 16 + c16;
#pragma unroll
      for (int kk = 0; kk < 2; ++kk) {
        const int cb = (kk * 4 + g) ^ (rb & 7);
        bfr[j][kk] = *reinterpret_cast<const short8*>(lb + rb * 128 + (cb << 4));
      }
    }
    asm volatile("s_waitcnt lgkmcnt(0)" ::: "memory");
    __builtin_amdgcn_sched_barrier(0);
    __builtin_amdgcn_s_setprio(1);
#pragma unroll
    for (int kk = 0; kk < 2; ++kk)
#pragma unroll
      for (int i = 0; i < 8; ++i)
#pragma unroll
        for (int j = 0; j < 3; ++j)
          acc[i][j] = __builtin_amdgcn_mfma_f32_16x16x32_bf16(af[i][kk], bfr[j][kk],
                                                              acc[i][j], 0, 0, 0);
    __builtin_amdgcn_s_setprio(0);
    if (t < 15) {
      __builtin_amdgcn_s_barrier();                       // all done reading buf
      if (t < 14) {
        stageT(buf, (t + 2) * 64);                        // refill just-freed buf
        asm volatile("s_waitcnt vmcnt(7)" ::: "memory");  // t+1 certified
      } else {
        asm volatile("s_waitcnt vmcnt(0)" ::: "memory");  // tail: t15 certified
      }
      __builtin_amdgcn_s_barrier();
    }
  }

  // epilogue: per-fragment segment routing (192-tiles straddle 1024 boundaries)
  const int rgrp = g * 4;
#pragma unroll
  for (int i = 0; i < 8; ++i) {
    const int tk0 = m0 + wm + i * 16 + rgrp;        // 4-aligned token base
    const int bb = tk0 >> 11;
    const int tw = tk0 & 2047;
    const int tpos = (tw & ~63) + perm64(tw & 63);
#pragma unroll
    for (int j = 0; j < 3; ++j) {
      const int gn = n0 + wn + j * 16 + c16;
      const int seg = gn >> 10;
      const float bv = ((seg == 0) ? b0 : (seg == 1) ? b1 : b2)[gn & 1023] *
                       ((seg == 0) ? QSCALE : 1.0f);
      if (gn >= 2048) {
        const int vdim = gn - 2048;
        const int h = vdim >> 6, d = vdim & 63;
        ushortx4 ov;
#pragma unroll
        for (int r = 0; r < 4; ++r) ov[r] = f2bf(acc[i][j][r] + bv);
        *reinterpret_cast<ushortx4*>(
            &Vt[((size_t)((bb * NH + h) * HD + d)) * TT + tpos]) = ov;
      } else {
#pragma unroll
        for (int r = 0; r < 4; ++r)
          out[(size_t)(tk0 + r) * QKVN + gn] = f2bf(acc[i][j][r] + bv);
      }
    }
  }
}

// ---------------- proj GEMM: 128x128 tile, counted-vmcnt, XCD-chunk swizzle -----------
// grid 256 linear; chunk of 32 = 8(m)x4(n): per-XCD working set 2MB A + 1MB B < L2.
__global__ __launch_bounds__(256) void gemm_proj(const unsigned short* __restrict__ A,
                                                 const unsigned short* __restrict__ W,
                                                 const float* __restrict__ bias,
                                                 float* __restrict__ outv) {
  __shared__ unsigned short lsA[2][128 * 64];
  __shared__ unsigned short lsB[2][128 * 64];
  const int tid = threadIdx.x;
  const int wave = tid >> 6, lane = tid & 63;
  const int orig = blockIdx.x;
  const int vid = (orig & 7) * 32 + (orig >> 3);
  const int chk = vid >> 5, wrm = vid & 31;
  const int m0 = ((chk & 3) * 8 + (wrm >> 2)) * 128;   // 32 m-blocks
  const int n0 = ((chk >> 2) * 4 + (wrm & 3)) * 128;   // 8 n-blocks
  const int wm = (wave >> 1) * 64, wn = (wave & 1) * 64;
  const int K = CC, N = CC;

  floatx4 acc[4][4];
#pragma unroll
  for (int i = 0; i < 4; ++i)
#pragma unroll
    for (int j = 0; j < 4; ++j)
      acc[i][j] = (floatx4){0.f, 0.f, 0.f, 0.f};

  const int sr = lane >> 3;
  const int sj = lane & 7;

  auto stageT = [&](int buf, int kt) {
#pragma unroll
    for (int t = 0; t < 4; ++t) {
      const int g4 = wave * 4 + t;
      const int r = g4 * 8 + sr;
      const int gj = (sj ^ (r & 7)) << 3;
      gload16(A + (size_t)(m0 + r) * K + kt + gj, (char*)lsA[buf] + g4 * 1024);
      gload16(W + (size_t)(n0 + r) * K + kt + gj, (char*)lsB[buf] + g4 * 1024);
    }
  };

  stageT(0, 0);
  stageT(1, 64);
  asm volatile("s_waitcnt vmcnt(8)" ::: "memory");
  __builtin_amdgcn_s_barrier();

#pragma unroll 2
  for (int t = 0; t < 16; ++t) {
    const int buf = t & 1;
    const char* la = (const char*)lsA[buf];
    const char* lb = (const char*)lsB[buf];
    short8 af[4][2], bfr[4][2];
#pragma unroll
    for (int i = 0; i < 4; ++i) {
      const int ra = wm + i * 16 + (lane & 15);
      const int rb = wn + i * 16 + (lane & 15);
#pragma unroll
      for (int kk = 0; kk < 2; ++kk) {
        const int ca = (kk * 4 + (lane >> 4)) ^ (ra & 7);
        const int cb = (kk * 4 + (lane >> 4)) ^ (rb & 7);
        af[i][kk] = *reinterpret_cast<const short8*>(la + ra * 128 + (ca << 4));
        bfr[i][kk] = *reinterpret_cast<const short8*>(lb + rb * 128 + (cb << 4));
      }
    }
    asm volatile("s_waitcnt lgkmcnt(0)" ::: "memory");
    __builtin_amdgcn_sched_barrier(0);
    __builtin_amdgcn_s_setprio(1);
#pragma unroll
    for (int kk = 0; kk < 2; ++kk)
#pragma unroll
      for (int i = 0; i < 4; ++i)
#pragma unroll
        for (int j = 0; j < 4; ++j)
          acc[i][j] = __builtin_amdgcn_mfma_f32_16x16x32_bf16(af[i][kk], bfr[j][kk],
                                                              acc[i][j], 0, 0, 0);
    __builtin_amdgcn_s_setprio(0);
    if (t < 15) {
      __builtin_amdgcn_s_barrier();
      if (t < 14) {
        stageT(buf, (t + 2) * 64);
        asm volatile("s_waitcnt vmcnt(8)" ::: "memory");
      } else {
        asm volatile("s_waitcnt vmcnt(0)" ::: "memory");
      }
      __builtin_amdgcn_s_barrier();
    }
  }

  const int col = lane & 15;
  const int rgrp = (lane >> 4) * 4;
#pragma unroll
  for (int i = 0; i < 4; ++i) {
    const int gm0 = m0 + wm + i * 16 + rgrp;
#pragma unroll
    for (int j = 0; j < 4; ++j) {
      const int gn = n0 + wn + j * 16 + col;
      const float bv = bias[gn];
#pragma unroll
      for (int r = 0; r < 4; ++r)
        outv[(size_t)(gm0 + r) * N + gn] = acc[i][j][r] + bv;
    }
  }
}

// ---------------- Flash attention: m=0 softmax, counted-vmcnt pipeline (R10 best) -----
// Grid (B*H, T/64): bh on blockIdx.x -> each bh's K/V pinned to one XCD L2.
// 4 waves; wave owns 16 q rows. Q pre-scaled by (1/8)log2e -> S log2-domain,
// P=2^S bounded, no running max. l via mfma(ones,P) on the matrix pipe.
__global__ __launch_bounds__(256) void attn_fwd(const unsigned short* __restrict__ QKV,
                                                const unsigned short* __restrict__ Vt,
                                                unsigned short* __restrict__ Ob) {
  __shared__ unsigned short lsK[2][64 * 64];
  __shared__ unsigned short lsV[2][64 * 64];
  const int tid = threadIdx.x;
  const int wave = tid >> 6, lane = tid & 63;
  const int g = lane >> 4;
  const int c16 = lane & 15;
  const int bh = blockIdx.x;
  const int b = bh >> 4, h = bh & 15;
  const int q0 = blockIdx.y * 64 + wave * 16;

  short8 qf[2];
  {
    const unsigned short* qp =
        QKV + (size_t)(b * TT + q0 + c16) * QKVN + h * HD + g * 8;
    qf[0] = *reinterpret_cast<const short8*>(qp);
    qf[1] = *reinterpret_cast<const short8*>(qp + 32);
  }

  short8 ones;
#pragma unroll
  for (int i = 0; i < 8; ++i) ones[i] = (short)0x3F80;  // bf16 1.0

  floatx4 o[4];
#pragma unroll
  for (int f = 0; f < 4; ++f) o[f] = (floatx4){0.f, 0.f, 0.f, 0.f};
  floatx4 lacc = (floatx4){0.f, 0.f, 0.f, 0.f};

  const int sr = lane >> 3, sj = lane & 7;

  auto stage = [&](int buf, int kt) {
#pragma unroll
    for (int t = 0; t < 2; ++t) {
      const int g8 = wave * 2 + t;
      const int r = g8 * 8 + sr;
      const int gj = (sj ^ (r & 7)) << 3;
      gload16(QKV + (size_t)(b * TT + kt + r) * QKVN + CC + h * HD + gj,
              (char*)lsK[buf] + g8 * 1024);
      gload16(Vt + ((size_t)bh * HD + r) * TT + kt + gj, (char*)lsV[buf] + g8 * 1024);
    }
  };

  auto compute = [&](const unsigned short* lk, const unsigned short* lv) {
    // S^T = K * Q^T  (log2 domain)
    floatx4 s[4];
#pragma unroll
    for (int cb = 0; cb < 4; ++cb) s[cb] = (floatx4){0.f, 0.f, 0.f, 0.f};
    __builtin_amdgcn_s_setprio(1);
#pragma unroll
    for (int kk = 0; kk < 2; ++kk) {
#pragma unroll
      for (int cb = 0; cb < 4; ++cb) {
        const int rk = cb * 16 + c16;
        const int ck = (kk * 4 + g) ^ (rk & 7);
        const short8 kf =
            *reinterpret_cast<const short8*>((const char*)lk + rk * 128 + (ck << 4));
        s[cb] = __builtin_amdgcn_mfma_f32_16x16x32_bf16(kf, qf[kk], s[cb], 0, 0, 0);
      }
    }
    __builtin_amdgcn_s_setprio(0);

    // P = 2^S and pack to bf16 pairs
    unsigned int w[4][2];
#pragma unroll
    for (int cb = 0; cb < 4; ++cb) {
#pragma unroll
      for (int r = 0; r < 4; ++r) s[cb][r] = fexp2(s[cb][r]);
      asm("v_cvt_pk_bf16_f32 %0, %1, %2"
          : "=v"(w[cb][0]) : "v"(s[cb][0]), "v"(s[cb][1]));
      asm("v_cvt_pk_bf16_f32 %0, %1, %2"
          : "=v"(w[cb][1]) : "v"(s[cb][2]), "v"(s[cb][3]));
    }

    // O^T += V^T * P^T ; l += ones * P^T (denominator on the matrix pipe)
#pragma unroll
    for (int kk = 0; kk < 2; ++kk) {
      unsigned int pa0 = w[2 * kk][0], pb0 = w[2 * kk + 1][0];
      unsigned int pa1 = w[2 * kk][1], pb1 = w[2 * kk + 1][1];
      asm("v_permlane32_swap_b32 %0, %1" : "+v"(pa0), "+v"(pb0));
      asm("v_permlane32_swap_b32 %0, %1" : "+v"(pa1), "+v"(pb1));
      union { unsigned int u[4]; short8 v; } pk;
      pk.u[0] = pa0; pk.u[1] = pa1; pk.u[2] = pb0; pk.u[3] = pb1;
      const short8 pbv = pk.v;
      __builtin_amdgcn_s_setprio(1);
#pragma unroll
      for (int f = 0; f < 4; ++f) {
        const int rv = f * 16 + c16;
        const int cv = (4 * kk + g) ^ (rv & 7);
        const short8 vf =
            *reinterpret_cast<const short8*>((const char*)lv + rv * 128 + (cv << 4));
        o[f] = __builtin_amdgcn_mfma_f32_16x16x32_bf16(vf, pbv, o[f], 0, 0, 0);
      }
      lacc = __builtin_amdgcn_mfma_f32_16x16x32_bf16(ones, pbv, lacc, 0, 0, 0);
      __builtin_amdgcn_s_setprio(0);
    }
  };

  stage(0, 0);

#pragma unroll 2
  for (int it = 0; it < TT / 64; ++it) {
    const int buf = it & 1;
    if (it < TT / 64 - 1) {
      stage(buf ^ 1, (it + 1) * 64);                      // prefetch stays in flight
      asm volatile("s_waitcnt vmcnt(4)" ::: "memory");    // only current tile landed
    } else {
      asm volatile("s_waitcnt vmcnt(0)" ::: "memory");
    }
    __builtin_amdgcn_s_barrier();                         // all waves: buf ready
    __builtin_amdgcn_sched_barrier(0);
    compute((const unsigned short*)lsK[buf], (const unsigned short*)lsV[buf]);
    __builtin_amdgcn_s_barrier();                         // all waves done reading buf
  }

  // epilogue: normalize, vectorized 8B stores
  {
    const float inv = 1.0f / lacc[0];
    const size_t gm = (size_t)(b * TT + q0 + c16) * CC;
#pragma unroll
    for (int f = 0; f < 4; ++f) {
      ushortx4 ov;
#pragma unroll
      for (int r = 0; r < 4; ++r) ov[r] = f2bf(o[f][r] * inv);
      *reinterpret_cast<ushortx4*>(&Ob[gm + h * HD + f * 16 + 4 * g]) = ov;
    }
  }
}

extern "C" void kernel_launch(void* const* d_in, const int* in_sizes, int n_in,
                              void* d_out, int out_size, void* d_ws, size_t ws_size,
                              hipStream_t stream) {
  (void)in_sizes; (void)n_in; (void)out_size; (void)ws_size;
  const float* x  = (const float*)d_in[0];
  const float* Wk = (const float*)d_in[1];
  const float* bk = (const float*)d_in[2];
  const float* Wq = (const float*)d_in[3];
  const float* bq = (const float*)d_in[4];
  const float* Wv = (const float*)d_in[5];
  const float* bv = (const float*)d_in[6];
  const float* Wp = (const float*)d_in[7];
  const float* bp = (const float*)d_in[8];
  float* out = (float*)d_out;

  char* ws = (char*)d_ws;
  const size_t MB = 1u << 20;
  unsigned short* xb    = (unsigned short*)(ws);            // 8 MB [4096][1024]
  unsigned short* Wqkvb = (unsigned short*)(ws + 8 * MB);   // 6 MB [3072][1024] (q,k,v)
  unsigned short* Wpb   = (unsigned short*)(ws + 14 * MB);  // 2 MB
  unsigned short* QKVb  = (unsigned short*)(ws + 16 * MB);  // 24 MB [4096][3072] (V third unused)
  unsigned short* Vtb   = (unsigned short*)(ws + 40 * MB);  // 8 MB [32][64][2048] permuted
  unsigned short* Ab    = (unsigned short*)(ws + 48 * MB);  // 8 MB [4096][1024]

  cvt_fused<<<8192, 256, 0, stream>>>(x, Wq, Wk, Wv, Wp, xb, Wqkvb, Wpb);

  // fused QKV GEMM (256x192, 256 blocks = 1/CU, XCD-chunked); V third -> permuted Vt
  gemm_qkv<<<256, 512, 0, stream>>>(xb, Wqkvb, bq, bk, bv, QKVb, Vtb);

  // bh on blockIdx.x: all q-chunks of one bh share an XCD -> K/V L2 locality
  attn_fwd<<<dim3(2 * NH, TT / 64), 256, 0, stream>>>(QKVb, Vtb, Ab);

  gemm_proj<<<256, 256, 0, stream>>>(Ab, Wpb, bp, out);
}

// Round 13
// 117.060 us; speedup vs baseline: 1.1143x; 1.0023x over previous
//
#include <hip/hip_runtime.h>
#include <hip/hip_bf16.h>
#include <stdint.h>

#define TT 2048
#define CC 1024
#define NH 16
#define HD 64
#define QKVN 3072

typedef __attribute__((ext_vector_type(8))) short short8;
typedef __attribute__((ext_vector_type(4))) float floatx4;
typedef __attribute__((ext_vector_type(4))) unsigned short ushortx4;

typedef const __attribute__((address_space(1))) void gas_void;
typedef __attribute__((address_space(3))) void las_void;

__device__ __forceinline__ void gload16(const void* g, void* l) {
  __builtin_amdgcn_global_load_lds((gas_void*)g, (las_void*)l, 16, 0, 0);
}

__device__ __forceinline__ unsigned short f2bf(float f) {
  union { float f; uint32_t u; } v; v.f = f;
  uint32_t u = v.u;
  uint32_t r = (u + 0x7fffu + ((u >> 16) & 1u)) >> 16;
  return (unsigned short)r;
}

__device__ __forceinline__ float fexp2(float x) {
#if __has_builtin(__builtin_amdgcn_exp2f)
  return __builtin_amdgcn_exp2f(x);
#else
  return exp2f(x);
#endif
}

#define QSCALE 0.18033688011112042f  // (1/8)*log2(e), folded into Wq/bq

// kv permutation within a 64-block: chunk c'=4kk+g holds runs [kA..kA+3, kA+8..kA+11]
__device__ __forceinline__ int perm64(int t) {
  const int kk = t >> 5, r5 = t & 31;
  const int g = ((r5 >> 3) & 2) | ((r5 >> 2) & 1);
  const int slot = (r5 & 3) | ((r5 >> 1) & 4);
  return kk * 32 + g * 8 + slot;
}

// ---------------- fused f32 -> bf16 conversion; Wq pre-scaled by QSCALE ----------------
__global__ __launch_bounds__(256) void cvt_fused(const float* __restrict__ x,
                                                 const float* __restrict__ wq,
                                                 const float* __restrict__ wk,
                                                 const float* __restrict__ wv,
                                                 const float* __restrict__ wp,
                                                 unsigned short* __restrict__ xb,
                                                 unsigned short* __restrict__ wqkvb,
                                                 unsigned short* __restrict__ wpb) {
  const int i = blockIdx.x * blockDim.x + threadIdx.x;  // f4 index, total 2097152
  if (i < 1048576) {            // x: 4096x1024
    const float4 v = reinterpret_cast<const float4*>(x)[i];
    ushortx4 o; o[0] = f2bf(v.x); o[1] = f2bf(v.y); o[2] = f2bf(v.z); o[3] = f2bf(v.w);
    reinterpret_cast<ushortx4*>(xb)[i] = o;
    return;
  }
  const int j = i - 1048576;     // 0..1048575 over 4 weight matrices
  const int seg = j >> 18;       // 262144 f4 per weight
  const int idx = j & 262143;
  const float* src = (seg == 0) ? wq : (seg == 1) ? wk : (seg == 2) ? wv : wp;
  const float sc = (seg == 0) ? QSCALE : 1.0f;
  const float4 v = reinterpret_cast<const float4*>(src)[idx];
  ushortx4 o;
  o[0] = f2bf(v.x * sc); o[1] = f2bf(v.y * sc); o[2] = f2bf(v.z * sc); o[3] = f2bf(v.w * sc);
  if (seg < 3)
    reinterpret_cast<ushortx4*>(wqkvb)[j] = o;       // q,k,v contiguous thirds
  else
    reinterpret_cast<ushortx4*>(wpb)[idx] = o;
}

// ---------------- QKV GEMM: 256x192 tile, grid 256, XCD-chunk swizzle -----------------
// Compiler-scheduled LDS->MFMA interleave (no manual lgkmcnt/sched_barrier);
// pointer-hoisted staging (base += 64/tile). Counted-vmcnt 2-deep pipeline.
__global__ __launch_bounds__(512) void gemm_qkv(const unsigned short* __restrict__ A,
                                                const unsigned short* __restrict__ W,
                                                const float* __restrict__ b0,
                                                const float* __restrict__ b1,
                                                const float* __restrict__ b2,
                                                unsigned short* __restrict__ out,
                                                unsigned short* __restrict__ Vt) {
  __shared__ unsigned short lsA[2][256 * 64];
  __shared__ unsigned short lsB[2][192 * 64];
  const int tid = threadIdx.x;
  const int wave = tid >> 6, lane = tid & 63;
  const int g = lane >> 4, c16 = lane & 15;
  // XCD-aware swizzle (bijective: 256 blocks, 8 XCDs)
  const int orig = blockIdx.x;
  const int vid = (orig & 7) * 32 + (orig >> 3);
  const int chk = vid >> 5, wrm = vid & 31;
  const int m0 = ((chk & 3) * 4 + (wrm & 3)) * 256;
  const int n0 = ((chk >> 2) * 8 + (wrm >> 2)) * 192;
  const int wm = (wave >> 2) * 128, wn = (wave & 3) * 48;

  floatx4 acc[8][3];
#pragma unroll
  for (int i = 0; i < 8; ++i)
#pragma unroll
    for (int j = 0; j < 3; ++j) acc[i][j] = (floatx4){0.f, 0.f, 0.f, 0.f};

  const int srow = lane >> 3, sj = lane & 7;
  const int gj = (sj ^ srow) << 3;              // row&7 == srow for all staged rows

  // hoisted per-lane staging bases (advance by 64 columns per staged tile)
  const unsigned short* aSrc = A + (size_t)(m0 + wave * 32 + srow) * CC + gj;
  const unsigned short* bSrc = W + (size_t)(n0 + wave * 24 + srow) * CC + gj;

  auto stageT = [&](int buf) {
    char* la = (char*)lsA[buf] + (wave * 4) * 1024;
    char* lb = (char*)lsB[buf] + (wave * 3) * 1024;
#pragma unroll
    for (int rho = 0; rho < 4; ++rho)
      gload16(aSrc + (size_t)rho * 8 * CC, la + rho * 1024);
#pragma unroll
    for (int rho = 0; rho < 3; ++rho)
      gload16(bSrc + (size_t)rho * 8 * CC, lb + rho * 1024);
    aSrc += 64;
    bSrc += 64;
  };

  stageT(0);
  stageT(1);
  asm volatile("s_waitcnt vmcnt(7)" ::: "memory");   // tile0 landed; tile1 in flight
  __builtin_amdgcn_s_barrier();

#pragma unroll 2
  for (int t = 0; t < 16; ++t) {
    const int buf = t & 1;
    const char* la = (const char*)lsA[buf];
    const char* lb = (const char*)lsB[buf];
    short8 af[8][2], bfr[3][2];
#pragma unroll
    for (int i = 0; i < 8; ++i) {
      const int ra = wm + i * 16 + c16;
#pragma unroll
      for (int kk = 0; kk < 2; ++kk) {
        const int ca = (kk * 4 + g) ^ (ra & 7);
        af[i][kk] = *reinterpret_cast<const short8*>(la + ra * 128 + (ca << 4));
      }
    }
#pragma unroll
    for (int j = 0; j < 3; ++j) {
      const int rb = wn + j * 16 + c16;
#pragma unroll
      for (int kk = 0; kk < 2; ++kk) {
        const int cb = (kk * 4 + g) ^ (rb & 7);
        bfr[j][kk] = *reinterpret_cast<const short8*>(lb + rb * 128 + (cb << 4));
      }
    }
    // compiler inserts fine-grained lgkmcnt between ds_read and dependent MFMA
    __builtin_amdgcn_s_setprio(1);
#pragma unroll
    for (int kk = 0; kk < 2; ++kk)
#pragma unroll
      for (int i = 0; i < 8; ++i)
#pragma unroll
        for (int j = 0; j < 3; ++j)
          acc[i][j] = __builtin_amdgcn_mfma_f32_16x16x32_bf16(af[i][kk], bfr[j][kk],
                                                              acc[i][j], 0, 0, 0);
    __builtin_amdgcn_s_setprio(0);
    if (t < 15) {
      __builtin_amdgcn_s_barrier();                       // all done reading buf
      if (t < 14) {
        stageT(buf);                                      // refill just-freed buf (t+2)
        asm volatile("s_waitcnt vmcnt(7)" ::: "memory");  // t+1 certified
      } else {
        asm volatile("s_waitcnt vmcnt(0)" ::: "memory");  // tail: t15 certified
      }
      __builtin_amdgcn_s_barrier();
    }
  }

  // epilogue: per-fragment segment routing (192-tiles straddle 1024 boundaries)
  const int rgrp = g * 4;
#pragma unroll
  for (int i = 0; i < 8; ++i) {
    const int tk0 = m0 + wm + i * 16 + rgrp;        // 4-aligned token base
    const int bb = tk0 >> 11;
    const int tw = tk0 & 2047;
    const int tpos = (tw & ~63) + perm64(tw & 63);
#pragma unroll
    for (int j = 0; j < 3; ++j) {
      const int gn = n0 + wn + j * 16 + c16;
      const int seg = gn >> 10;
      const float bv = ((seg == 0) ? b0 : (seg == 1) ? b1 : b2)[gn & 1023] *
                       ((seg == 0) ? QSCALE : 1.0f);
      if (gn >= 2048) {
        const int vdim = gn - 2048;
        const int h = vdim >> 6, d = vdim & 63;
        ushortx4 ov;
#pragma unroll
        for (int r = 0; r < 4; ++r) ov[r] = f2bf(acc[i][j][r] + bv);
        *reinterpret_cast<ushortx4*>(
            &Vt[((size_t)((bb * NH + h) * HD + d)) * TT + tpos]) = ov;
      } else {
#pragma unroll
        for (int r = 0; r < 4; ++r)
          out[(size_t)(tk0 + r) * QKVN + gn] = f2bf(acc[i][j][r] + bv);
      }
    }
  }
}

// ---------------- proj GEMM: 128x128 tile, counted-vmcnt, XCD-chunk swizzle -----------
__global__ __launch_bounds__(256) void gemm_proj(const unsigned short* __restrict__ A,
                                                 const unsigned short* __restrict__ W,
                                                 const float* __restrict__ bias,
                                                 float* __restrict__ outv) {
  __shared__ unsigned short lsA[2][128 * 64];
  __shared__ unsigned short lsB[2][128 * 64];
  const int tid = threadIdx.x;
  const int wave = tid >> 6, lane = tid & 63;
  const int orig = blockIdx.x;
  const int vid = (orig & 7) * 32 + (orig >> 3);
  const int chk = vid >> 5, wrm = vid & 31;
  const int m0 = ((chk & 3) * 8 + (wrm >> 2)) * 128;   // 32 m-blocks
  const int n0 = ((chk >> 2) * 4 + (wrm & 3)) * 128;   // 8 n-blocks
  const int wm = (wave >> 1) * 64, wn = (wave & 1) * 64;
  const int K = CC, N = CC;

  floatx4 acc[4][4];
#pragma unroll
  for (int i = 0; i < 4; ++i)
#pragma unroll
    for (int j = 0; j < 4; ++j)
      acc[i][j] = (floatx4){0.f, 0.f, 0.f, 0.f};

  const int sr = lane >> 3;
  const int sj = lane & 7;
  const int gj = (sj ^ sr) << 3;

  const unsigned short* aSrc = A + (size_t)(m0 + wave * 32 + sr) * K + gj;
  const unsigned short* bSrc = W + (size_t)(n0 + wave * 32 + sr) * K + gj;

  auto stageT = [&](int buf) {
    char* la = (char*)lsA[buf] + (wave * 4) * 1024;
    char* lb = (char*)lsB[buf] + (wave * 4) * 1024;
#pragma unroll
    for (int t = 0; t < 4; ++t) {
      gload16(aSrc + (size_t)t * 8 * K, la + t * 1024);
      gload16(bSrc + (size_t)t * 8 * K, lb + t * 1024);
    }
    aSrc += 64;
    bSrc += 64;
  };

  stageT(0);
  stageT(1);
  asm volatile("s_waitcnt vmcnt(8)" ::: "memory");
  __builtin_amdgcn_s_barrier();

#pragma unroll 2
  for (int t = 0; t < 16; ++t) {
    const int buf = t & 1;
    const char* la = (const char*)lsA[buf];
    const char* lb = (const char*)lsB[buf];
    short8 af[4][2], bfr[4][2];
#pragma unroll
    for (int i = 0; i < 4; ++i) {
      const int ra = wm + i * 16 + (lane & 15);
      const int rb = wn + i * 16 + (lane & 15);
#pragma unroll
      for (int kk = 0; kk < 2; ++kk) {
        const int ca = (kk * 4 + (lane >> 4)) ^ (ra & 7);
        const int cb = (kk * 4 + (lane >> 4)) ^ (rb & 7);
        af[i][kk] = *reinterpret_cast<const short8*>(la + ra * 128 + (ca << 4));
        bfr[i][kk] = *reinterpret_cast<const short8*>(lb + rb * 128 + (cb << 4));
      }
    }
    __builtin_amdgcn_s_setprio(1);
#pragma unroll
    for (int kk = 0; kk < 2; ++kk)
#pragma unroll
      for (int i = 0; i < 4; ++i)
#pragma unroll
        for (int j = 0; j < 4; ++j)
          acc[i][j] = __builtin_amdgcn_mfma_f32_16x16x32_bf16(af[i][kk], bfr[j][kk],
                                                              acc[i][j], 0, 0, 0);
    __builtin_amdgcn_s_setprio(0);
    if (t < 15) {
      __builtin_amdgcn_s_barrier();
      if (t < 14) {
        stageT(buf);
        asm volatile("s_waitcnt vmcnt(8)" ::: "memory");
      } else {
        asm volatile("s_waitcnt vmcnt(0)" ::: "memory");
      }
      __builtin_amdgcn_s_barrier();
    }
  }

  const int col = lane & 15;
  const int rgrp = (lane >> 4) * 4;
#pragma unroll
  for (int i = 0; i < 4; ++i) {
    const int gm0 = m0 + wm + i * 16 + rgrp;
#pragma unroll
    for (int j = 0; j < 4; ++j) {
      const int gn = n0 + wn + j * 16 + col;
      const float bv = bias[gn];
#pragma unroll
      for (int r = 0; r < 4; ++r)
        outv[(size_t)(gm0 + r) * N + gn] = acc[i][j][r] + bv;
    }
  }
}

// ---------------- Flash attention: m=0 softmax, counted-vmcnt pipeline ----------------
// Grid (B*H, T/64): bh on blockIdx.x -> each bh's K/V pinned to one XCD L2.
// 4 waves; wave owns 16 q rows. Q pre-scaled by (1/8)log2e -> S log2-domain,
// P=2^S bounded, no running max. l via mfma(ones,P). Pointer-hoisted staging.
__global__ __launch_bounds__(256) void attn_fwd(const unsigned short* __restrict__ QKV,
                                                const unsigned short* __restrict__ Vt,
                                                unsigned short* __restrict__ Ob) {
  __shared__ unsigned short lsK[2][64 * 64];
  __shared__ unsigned short lsV[2][64 * 64];
  const int tid = threadIdx.x;
  const int wave = tid >> 6, lane = tid & 63;
  const int g = lane >> 4;
  const int c16 = lane & 15;
  const int bh = blockIdx.x;
  const int b = bh >> 4, h = bh & 15;
  const int q0 = blockIdx.y * 64 + wave * 16;

  short8 qf[2];
  {
    const unsigned short* qp =
        QKV + (size_t)(b * TT + q0 + c16) * QKVN + h * HD + g * 8;
    qf[0] = *reinterpret_cast<const short8*>(qp);
    qf[1] = *reinterpret_cast<const short8*>(qp + 32);
  }

  short8 ones;
#pragma unroll
  for (int i = 0; i < 8; ++i) ones[i] = (short)0x3F80;  // bf16 1.0

  floatx4 o[4];
#pragma unroll
  for (int f = 0; f < 4; ++f) o[f] = (floatx4){0.f, 0.f, 0.f, 0.f};
  floatx4 lacc = (floatx4){0.f, 0.f, 0.f, 0.f};

  const int sr = lane >> 3, sj = lane & 7;
  const int gj = (sj ^ sr) << 3;                // staged rows have row&7 == sr

  // hoisted per-lane staging bases; advance per tile (K: +64 tokens, V: +64 cols)
  const unsigned short* kSrc =
      QKV + (size_t)(b * TT + wave * 16 + sr) * QKVN + CC + h * HD + gj;
  const unsigned short* vSrc = Vt + ((size_t)bh * HD + wave * 16 + sr) * TT + gj;

  auto stage = [&](int buf) {
    char* lk = (char*)lsK[buf] + (wave * 2) * 1024;
    char* lv = (char*)lsV[buf] + (wave * 2) * 1024;
    gload16(kSrc, lk);
    gload16(kSrc + (size_t)8 * QKVN, lk + 1024);
    gload16(vSrc, lv);
    gload16(vSrc + (size_t)8 * TT, lv + 1024);
    kSrc += (size_t)64 * QKVN;
    vSrc += 64;
  };

  auto compute = [&](const unsigned short* lk, const unsigned short* lv) {
    // S^T = K * Q^T  (log2 domain)
    floatx4 s[4];
#pragma unroll
    for (int cb = 0; cb < 4; ++cb) s[cb] = (floatx4){0.f, 0.f, 0.f, 0.f};
    __builtin_amdgcn_s_setprio(1);
#pragma unroll
    for (int kk = 0; kk < 2; ++kk) {
#pragma unroll
      for (int cb = 0; cb < 4; ++cb) {
        const int rk = cb * 16 + c16;
        const int ck = (kk * 4 + g) ^ (rk & 7);
        const short8 kf =
            *reinterpret_cast<const short8*>((const char*)lk + rk * 128 + (ck << 4));
        s[cb] = __builtin_amdgcn_mfma_f32_16x16x32_bf16(kf, qf[kk], s[cb], 0, 0, 0);
      }
    }
    __builtin_amdgcn_s_setprio(0);

    // P = 2^S and pack to bf16 pairs
    unsigned int w[4][2];
#pragma unroll
    for (int cb = 0; cb < 4; ++cb) {
#pragma unroll
      for (int r = 0; r < 4; ++r) s[cb][r] = fexp2(s[cb][r]);
      asm("v_cvt_pk_bf16_f32 %0, %1, %2"
          : "=v"(w[cb][0]) : "v"(s[cb][0]), "v"(s[cb][1]));
      asm("v_cvt_pk_bf16_f32 %0, %1, %2"
          : "=v"(w[cb][1]) : "v"(s[cb][2]), "v"(s[cb][3]));
    }

    // O^T += V^T * P^T ; l += ones * P^T (denominator on the matrix pipe)
#pragma unroll
    for (int kk = 0; kk < 2; ++kk) {
      unsigned int pa0 = w[2 * kk][0], pb0 = w[2 * kk + 1][0];
      unsigned int pa1 = w[2 * kk][1], pb1 = w[2 * kk + 1][1];
      asm("v_permlane32_swap_b32 %0, %1" : "+v"(pa0), "+v"(pb0));
      asm("v_permlane32_swap_b32 %0, %1" : "+v"(pa1), "+v"(pb1));
      union { unsigned int u[4]; short8 v; } pk;
      pk.u[0] = pa0; pk.u[1] = pa1; pk.u[2] = pb0; pk.u[3] = pb1;
      const short8 pbv = pk.v;
      __builtin_amdgcn_s_setprio(1);
#pragma unroll
      for (int f = 0; f < 4; ++f) {
        const int rv = f * 16 + c16;
        const int cv = (4 * kk + g) ^ (rv & 7);
        const short8 vf =
            *reinterpret_cast<const short8*>((const char*)lv + rv * 128 + (cv << 4));
        o[f] = __builtin_amdgcn_mfma_f32_16x16x32_bf16(vf, pbv, o[f], 0, 0, 0);
      }
      lacc = __builtin_amdgcn_mfma_f32_16x16x32_bf16(ones, pbv, lacc, 0, 0, 0);
      __builtin_amdgcn_s_setprio(0);
    }
  };

  stage(0);

#pragma unroll 2
  for (int it = 0; it < TT / 64; ++it) {
    const int buf = it & 1;
    if (it < TT / 64 - 1) {
      stage(buf ^ 1);                                     // prefetch stays in flight
      asm volatile("s_waitcnt vmcnt(4)" ::: "memory");    // only current tile landed
    } else {
      asm volatile("s_waitcnt vmcnt(0)" ::: "memory");
    }
    __builtin_amdgcn_s_barrier();                         // all waves: buf ready
    compute((const unsigned short*)lsK[buf], (const unsigned short*)lsV[buf]);
    __builtin_amdgcn_s_barrier();                         // all waves done reading buf
  }

  // epilogue: normalize, vectorized 8B stores
  {
    const float inv = 1.0f / lacc[0];
    const size_t gm = (size_t)(b * TT + q0 + c16) * CC;
#pragma unroll
    for (int f = 0; f < 4; ++f) {
      ushortx4 ov;
#pragma unroll
      for (int r = 0; r < 4; ++r) ov[r] = f2bf(o[f][r] * inv);
      *reinterpret_cast<ushortx4*>(&Ob[gm + h * HD + f * 16 + 4 * g]) = ov;
    }
  }
}

extern "C" void kernel_launch(void* const* d_in, const int* in_sizes, int n_in,
                              void* d_out, int out_size, void* d_ws, size_t ws_size,
                              hipStream_t stream) {
  (void)in_sizes; (void)n_in; (void)out_size; (void)ws_size;
  const float* x  = (const float*)d_in[0];
  const float* Wk = (const float*)d_in[1];
  const float* bk = (const float*)d_in[2];
  const float* Wq = (const float*)d_in[3];
  const float* bq = (const float*)d_in[4];
  const float* Wv = (const float*)d_in[5];
  const float* bv = (const float*)d_in[6];
  const float* Wp = (const float*)d_in[7];
  const float* bp = (const float*)d_in[8];
  float* out = (float*)d_out;

  char* ws = (char*)d_ws;
  const size_t MB = 1u << 20;
  unsigned short* xb    = (unsigned short*)(ws);            // 8 MB [4096][1024]
  unsigned short* Wqkvb = (unsigned short*)(ws + 8 * MB);   // 6 MB [3072][1024] (q,k,v)
  unsigned short* Wpb   = (unsigned short*)(ws + 14 * MB);  // 2 MB
  unsigned short* QKVb  = (unsigned short*)(ws + 16 * MB);  // 24 MB [4096][3072] (V third unused)
  unsigned short* Vtb   = (unsigned short*)(ws + 40 * MB);  // 8 MB [32][64][2048] permuted
  unsigned short* Ab    = (unsigned short*)(ws + 48 * MB);  // 8 MB [4096][1024]

  cvt_fused<<<8192, 256, 0, stream>>>(x, Wq, Wk, Wv, Wp, xb, Wqkvb, Wpb);

  // fused QKV GEMM (256x192, 256 blocks = 1/CU, XCD-chunked); V third -> permuted Vt
  gemm_qkv<<<256, 512, 0, stream>>>(xb, Wqkvb, bq, bk, bv, QKVb, Vtb);

  // bh on blockIdx.x: all q-chunks of one bh share an XCD -> K/V L2 locality
  attn_fwd<<<dim3(2 * NH, TT / 64), 256, 0, stream>>>(QKVb, Vtb, Ab);

  gemm_proj<<<256, 256, 0, stream>>>(Ab, Wpb, bp, out);
}

// Round 14
// 116.202 us; speedup vs baseline: 1.1225x; 1.0074x over previous
//
#include <hip/hip_runtime.h>
#include <hip/hip_bf16.h>
#include <stdint.h>

#define TT 2048
#define CC 1024
#define NH 16
#define HD 64
#define QKVN 3072

typedef __attribute__((ext_vector_type(8))) short short8;
typedef __attribute__((ext_vector_type(4))) float floatx4;
typedef __attribute__((ext_vector_type(4))) unsigned short ushortx4;

typedef const __attribute__((address_space(1))) void gas_void;
typedef __attribute__((address_space(3))) void las_void;

__device__ __forceinline__ void gload16(const void* g, void* l) {
  __builtin_amdgcn_global_load_lds((gas_void*)g, (las_void*)l, 16, 0, 0);
}

__device__ __forceinline__ unsigned short f2bf(float f) {
  union { float f; uint32_t u; } v; v.f = f;
  uint32_t u = v.u;
  uint32_t r = (u + 0x7fffu + ((u >> 16) & 1u)) >> 16;
  return (unsigned short)r;
}

__device__ __forceinline__ float fexp2(float x) {
#if __has_builtin(__builtin_amdgcn_exp2f)
  return __builtin_amdgcn_exp2f(x);
#else
  return exp2f(x);
#endif
}

#define QSCALE 0.18033688011112042f  // (1/8)*log2(e), folded into Wq/bq

// kv permutation within a 64-block: chunk c'=4kk+g holds runs [kA..kA+3, kA+8..kA+11]
__device__ __forceinline__ int perm64(int t) {
  const int kk = t >> 5, r5 = t & 31;
  const int g = ((r5 >> 3) & 2) | ((r5 >> 2) & 1);
  const int slot = (r5 & 3) | ((r5 >> 1) & 4);
  return kk * 32 + g * 8 + slot;
}

// ---------------- fused f32 -> bf16 conversion; Wq pre-scaled by QSCALE ----------------
__global__ __launch_bounds__(256) void cvt_fused(const float* __restrict__ x,
                                                 const float* __restrict__ wq,
                                                 const float* __restrict__ wk,
                                                 const float* __restrict__ wv,
                                                 const float* __restrict__ wp,
                                                 unsigned short* __restrict__ xb,
                                                 unsigned short* __restrict__ wqkvb,
                                                 unsigned short* __restrict__ wpb) {
  const int i = blockIdx.x * blockDim.x + threadIdx.x;  // f4 index, total 2097152
  if (i < 1048576) {            // x: 4096x1024
    const float4 v = reinterpret_cast<const float4*>(x)[i];
    ushortx4 o; o[0] = f2bf(v.x); o[1] = f2bf(v.y); o[2] = f2bf(v.z); o[3] = f2bf(v.w);
    reinterpret_cast<ushortx4*>(xb)[i] = o;
    return;
  }
  const int j = i - 1048576;     // 0..1048575 over 4 weight matrices
  const int seg = j >> 18;       // 262144 f4 per weight
  const int idx = j & 262143;
  const float* src = (seg == 0) ? wq : (seg == 1) ? wk : (seg == 2) ? wv : wp;
  const float sc = (seg == 0) ? QSCALE : 1.0f;
  const float4 v = reinterpret_cast<const float4*>(src)[idx];
  ushortx4 o;
  o[0] = f2bf(v.x * sc); o[1] = f2bf(v.y * sc); o[2] = f2bf(v.z * sc); o[3] = f2bf(v.w * sc);
  if (seg < 3)
    reinterpret_cast<ushortx4*>(wqkvb)[j] = o;       // q,k,v contiguous thirds
  else
    reinterpret_cast<ushortx4*>(wpb)[idx] = o;
}

// ---------------- QKV GEMM: 256x192 tile, grid 256, XCD-chunk swizzle -----------------
__global__ __launch_bounds__(512) void gemm_qkv(const unsigned short* __restrict__ A,
                                                const unsigned short* __restrict__ W,
                                                const float* __restrict__ b0,
                                                const float* __restrict__ b1,
                                                const float* __restrict__ b2,
                                                unsigned short* __restrict__ out,
                                                unsigned short* __restrict__ Vt) {
  __shared__ unsigned short lsA[2][256 * 64];
  __shared__ unsigned short lsB[2][192 * 64];
  const int tid = threadIdx.x;
  const int wave = tid >> 6, lane = tid & 63;
  const int g = lane >> 4, c16 = lane & 15;
  // XCD-aware swizzle (bijective: 256 blocks, 8 XCDs)
  const int orig = blockIdx.x;
  const int vid = (orig & 7) * 32 + (orig >> 3);
  const int chk = vid >> 5, wrm = vid & 31;
  const int m0 = ((chk & 3) * 4 + (wrm & 3)) * 256;
  const int n0 = ((chk >> 2) * 8 + (wrm >> 2)) * 192;
  const int wm = (wave >> 2) * 128, wn = (wave & 3) * 48;

  floatx4 acc[8][3];
#pragma unroll
  for (int i = 0; i < 8; ++i)
#pragma unroll
    for (int j = 0; j < 3; ++j) acc[i][j] = (floatx4){0.f, 0.f, 0.f, 0.f};

  const int srow = lane >> 3, sj = lane & 7;
  const int gj = (sj ^ srow) << 3;              // row&7 == srow for all staged rows

  const unsigned short* aSrc = A + (size_t)(m0 + wave * 32 + srow) * CC + gj;
  const unsigned short* bSrc = W + (size_t)(n0 + wave * 24 + srow) * CC + gj;

  auto stageT = [&](int buf) {
    char* la = (char*)lsA[buf] + (wave * 4) * 1024;
    char* lb = (char*)lsB[buf] + (wave * 3) * 1024;
#pragma unroll
    for (int rho = 0; rho < 4; ++rho)
      gload16(aSrc + (size_t)rho * 8 * CC, la + rho * 1024);
#pragma unroll
    for (int rho = 0; rho < 3; ++rho)
      gload16(bSrc + (size_t)rho * 8 * CC, lb + rho * 1024);
    aSrc += 64;
    bSrc += 64;
  };

  stageT(0);
  stageT(1);
  asm volatile("s_waitcnt vmcnt(7)" ::: "memory");   // tile0 landed; tile1 in flight
  __builtin_amdgcn_s_barrier();

#pragma unroll 2
  for (int t = 0; t < 16; ++t) {
    const int buf = t & 1;
    const char* la = (const char*)lsA[buf];
    const char* lb = (const char*)lsB[buf];
    short8 af[8][2], bfr[3][2];
#pragma unroll
    for (int i = 0; i < 8; ++i) {
      const int ra = wm + i * 16 + c16;
#pragma unroll
      for (int kk = 0; kk < 2; ++kk) {
        const int ca = (kk * 4 + g) ^ (ra & 7);
        af[i][kk] = *reinterpret_cast<const short8*>(la + ra * 128 + (ca << 4));
      }
    }
#pragma unroll
    for (int j = 0; j < 3; ++j) {
      const int rb = wn + j * 16 + c16;
#pragma unroll
      for (int kk = 0; kk < 2; ++kk) {
        const int cb = (kk * 4 + g) ^ (rb & 7);
        bfr[j][kk] = *reinterpret_cast<const short8*>(lb + rb * 128 + (cb << 4));
      }
    }
    __builtin_amdgcn_s_setprio(1);
#pragma unroll
    for (int kk = 0; kk < 2; ++kk)
#pragma unroll
      for (int i = 0; i < 8; ++i)
#pragma unroll
        for (int j = 0; j < 3; ++j)
          acc[i][j] = __builtin_amdgcn_mfma_f32_16x16x32_bf16(af[i][kk], bfr[j][kk],
                                                              acc[i][j], 0, 0, 0);
    __builtin_amdgcn_s_setprio(0);
    if (t < 15) {
      __builtin_amdgcn_s_barrier();                       // all done reading buf
      if (t < 14) {
        stageT(buf);                                      // refill just-freed buf (t+2)
        asm volatile("s_waitcnt vmcnt(7)" ::: "memory");  // t+1 certified
      } else {
        asm volatile("s_waitcnt vmcnt(0)" ::: "memory");  // tail: t15 certified
      }
      __builtin_amdgcn_s_barrier();
    }
  }

  // epilogue: per-fragment segment routing (192-tiles straddle 1024 boundaries)
  const int rgrp = g * 4;
#pragma unroll
  for (int i = 0; i < 8; ++i) {
    const int tk0 = m0 + wm + i * 16 + rgrp;        // 4-aligned token base
    const int bb = tk0 >> 11;
    const int tw = tk0 & 2047;
    const int tpos = (tw & ~63) + perm64(tw & 63);
#pragma unroll
    for (int j = 0; j < 3; ++j) {
      const int gn = n0 + wn + j * 16 + c16;
      const int seg = gn >> 10;
      const float bv = ((seg == 0) ? b0 : (seg == 1) ? b1 : b2)[gn & 1023] *
                       ((seg == 0) ? QSCALE : 1.0f);
      if (gn >= 2048) {
        const int vdim = gn - 2048;
        const int h = vdim >> 6, d = vdim & 63;
        ushortx4 ov;
#pragma unroll
        for (int r = 0; r < 4; ++r) ov[r] = f2bf(acc[i][j][r] + bv);
        *reinterpret_cast<ushortx4*>(
            &Vt[((size_t)((bb * NH + h) * HD + d)) * TT + tpos]) = ov;
      } else {
#pragma unroll
        for (int r = 0; r < 4; ++r)
          out[(size_t)(tk0 + r) * QKVN + gn] = f2bf(acc[i][j][r] + bv);
      }
    }
  }
}

// ---------------- proj GEMM: 128x128 tile, counted-vmcnt, XCD-chunk swizzle -----------
__global__ __launch_bounds__(256) void gemm_proj(const unsigned short* __restrict__ A,
                                                 const unsigned short* __restrict__ W,
                                                 const float* __restrict__ bias,
                                                 float* __restrict__ outv) {
  __shared__ unsigned short lsA[2][128 * 64];
  __shared__ unsigned short lsB[2][128 * 64];
  const int tid = threadIdx.x;
  const int wave = tid >> 6, lane = tid & 63;
  const int orig = blockIdx.x;
  const int vid = (orig & 7) * 32 + (orig >> 3);
  const int chk = vid >> 5, wrm = vid & 31;
  const int m0 = ((chk & 3) * 8 + (wrm >> 2)) * 128;   // 32 m-blocks
  const int n0 = ((chk >> 2) * 4 + (wrm & 3)) * 128;   // 8 n-blocks
  const int wm = (wave >> 1) * 64, wn = (wave & 1) * 64;
  const int K = CC, N = CC;

  floatx4 acc[4][4];
#pragma unroll
  for (int i = 0; i < 4; ++i)
#pragma unroll
    for (int j = 0; j < 4; ++j)
      acc[i][j] = (floatx4){0.f, 0.f, 0.f, 0.f};

  const int sr = lane >> 3;
  const int sj = lane & 7;
  const int gj = (sj ^ sr) << 3;

  const unsigned short* aSrc = A + (size_t)(m0 + wave * 32 + sr) * K + gj;
  const unsigned short* bSrc = W + (size_t)(n0 + wave * 32 + sr) * K + gj;

  auto stageT = [&](int buf) {
    char* la = (char*)lsA[buf] + (wave * 4) * 1024;
    char* lb = (char*)lsB[buf] + (wave * 4) * 1024;
#pragma unroll
    for (int t = 0; t < 4; ++t) {
      gload16(aSrc + (size_t)t * 8 * K, la + t * 1024);
      gload16(bSrc + (size_t)t * 8 * K, lb + t * 1024);
    }
    aSrc += 64;
    bSrc += 64;
  };

  stageT(0);
  stageT(1);
  asm volatile("s_waitcnt vmcnt(8)" ::: "memory");
  __builtin_amdgcn_s_barrier();

#pragma unroll 2
  for (int t = 0; t < 16; ++t) {
    const int buf = t & 1;
    const char* la = (const char*)lsA[buf];
    const char* lb = (const char*)lsB[buf];
    short8 af[4][2], bfr[4][2];
#pragma unroll
    for (int i = 0; i < 4; ++i) {
      const int ra = wm + i * 16 + (lane & 15);
      const int rb = wn + i * 16 + (lane & 15);
#pragma unroll
      for (int kk = 0; kk < 2; ++kk) {
        const int ca = (kk * 4 + (lane >> 4)) ^ (ra & 7);
        const int cb = (kk * 4 + (lane >> 4)) ^ (rb & 7);
        af[i][kk] = *reinterpret_cast<const short8*>(la + ra * 128 + (ca << 4));
        bfr[i][kk] = *reinterpret_cast<const short8*>(lb + rb * 128 + (cb << 4));
      }
    }
    __builtin_amdgcn_s_setprio(1);
#pragma unroll
    for (int kk = 0; kk < 2; ++kk)
#pragma unroll
      for (int i = 0; i < 4; ++i)
#pragma unroll
        for (int j = 0; j < 4; ++j)
          acc[i][j] = __builtin_amdgcn_mfma_f32_16x16x32_bf16(af[i][kk], bfr[j][kk],
                                                              acc[i][j], 0, 0, 0);
    __builtin_amdgcn_s_setprio(0);
    if (t < 15) {
      __builtin_amdgcn_s_barrier();
      if (t < 14) {
        stageT(buf);
        asm volatile("s_waitcnt vmcnt(8)" ::: "memory");
      } else {
        asm volatile("s_waitcnt vmcnt(0)" ::: "memory");
      }
      __builtin_amdgcn_s_barrier();
    }
  }

  const int col = lane & 15;
  const int rgrp = (lane >> 4) * 4;
#pragma unroll
  for (int i = 0; i < 4; ++i) {
    const int gm0 = m0 + wm + i * 16 + rgrp;
#pragma unroll
    for (int j = 0; j < 4; ++j) {
      const int gn = n0 + wn + j * 16 + col;
      const float bv = bias[gn];
#pragma unroll
      for (int r = 0; r < 4; ++r)
        outv[(size_t)(gm0 + r) * N + gn] = acc[i][j][r] + bv;
    }
  }
}

// ---------------- Flash attention: single-barrier/tile, K 2-deep (3 buf), V 1-deep ----
// Grid (B*H, T/64): bh on blockIdx.x -> each bh's K/V pinned to one XCD L2.
// 4 waves; wave owns 16 q rows. Q pre-scaled by (1/8)log2e -> S log2-domain,
// P=2^S bounded, no running max. l via mfma(ones,P).
// Per iter: {vmcnt(2) [certify K(t),V(t); leave K(t+1) in flight]; barrier
// [all waves' tile-t loads landed AND compute(t-1) done everywhere]; stageV(t+1);
// stageK(t+2); compute(t)}. V issued before K each iter so the in-order vmcnt
// drain order works out. LDS 40 KB -> still 4 blocks/CU.
__global__ __launch_bounds__(256) void attn_fwd(const unsigned short* __restrict__ QKV,
                                                const unsigned short* __restrict__ Vt,
                                                unsigned short* __restrict__ Ob) {
  __shared__ unsigned short lsK[3][64 * 64];
  __shared__ unsigned short lsV[2][64 * 64];
  const int tid = threadIdx.x;
  const int wave = tid >> 6, lane = tid & 63;
  const int g = lane >> 4;
  const int c16 = lane & 15;
  const int bh = blockIdx.x;
  const int b = bh >> 4, h = bh & 15;
  const int q0 = blockIdx.y * 64 + wave * 16;

  short8 qf[2];
  {
    const unsigned short* qp =
        QKV + (size_t)(b * TT + q0 + c16) * QKVN + h * HD + g * 8;
    qf[0] = *reinterpret_cast<const short8*>(qp);
    qf[1] = *reinterpret_cast<const short8*>(qp + 32);
  }

  short8 ones;
#pragma unroll
  for (int i = 0; i < 8; ++i) ones[i] = (short)0x3F80;  // bf16 1.0

  floatx4 o[4];
#pragma unroll
  for (int f = 0; f < 4; ++f) o[f] = (floatx4){0.f, 0.f, 0.f, 0.f};
  floatx4 lacc = (floatx4){0.f, 0.f, 0.f, 0.f};

  const int sr = lane >> 3, sj = lane & 7;
  const int gj = (sj ^ sr) << 3;                // staged rows have row&7 == sr

  const unsigned short* kSrc =
      QKV + (size_t)(b * TT + wave * 16 + sr) * QKVN + CC + h * HD + gj;
  const unsigned short* vSrc = Vt + ((size_t)bh * HD + wave * 16 + sr) * TT + gj;

  auto stageK = [&](int buf) {
    char* lk = (char*)lsK[buf] + (wave * 2) * 1024;
    gload16(kSrc, lk);
    gload16(kSrc + (size_t)8 * QKVN, lk + 1024);
    kSrc += (size_t)64 * QKVN;
  };
  auto stageV = [&](int buf) {
    char* lv = (char*)lsV[buf] + (wave * 2) * 1024;
    gload16(vSrc, lv);
    gload16(vSrc + (size_t)8 * TT, lv + 1024);
    vSrc += 64;
  };

  auto compute = [&](const unsigned short* lk, const unsigned short* lv) {
    // S^T = K * Q^T  (log2 domain)
    floatx4 s[4];
#pragma unroll
    for (int cb = 0; cb < 4; ++cb) s[cb] = (floatx4){0.f, 0.f, 0.f, 0.f};
    __builtin_amdgcn_s_setprio(1);
#pragma unroll
    for (int kk = 0; kk < 2; ++kk) {
#pragma unroll
      for (int cb = 0; cb < 4; ++cb) {
        const int rk = cb * 16 + c16;
        const int ck = (kk * 4 + g) ^ (rk & 7);
        const short8 kf =
            *reinterpret_cast<const short8*>((const char*)lk + rk * 128 + (ck << 4));
        s[cb] = __builtin_amdgcn_mfma_f32_16x16x32_bf16(kf, qf[kk], s[cb], 0, 0, 0);
      }
    }
    __builtin_amdgcn_s_setprio(0);

    // P = 2^S and pack to bf16 pairs
    unsigned int w[4][2];
#pragma unroll
    for (int cb = 0; cb < 4; ++cb) {
#pragma unroll
      for (int r = 0; r < 4; ++r) s[cb][r] = fexp2(s[cb][r]);
      asm("v_cvt_pk_bf16_f32 %0, %1, %2"
          : "=v"(w[cb][0]) : "v"(s[cb][0]), "v"(s[cb][1]));
      asm("v_cvt_pk_bf16_f32 %0, %1, %2"
          : "=v"(w[cb][1]) : "v"(s[cb][2]), "v"(s[cb][3]));
    }

    // O^T += V^T * P^T ; l += ones * P^T (denominator on the matrix pipe)
#pragma unroll
    for (int kk = 0; kk < 2; ++kk) {
      unsigned int pa0 = w[2 * kk][0], pb0 = w[2 * kk + 1][0];
      unsigned int pa1 = w[2 * kk][1], pb1 = w[2 * kk + 1][1];
      asm("v_permlane32_swap_b32 %0, %1" : "+v"(pa0), "+v"(pb0));
      asm("v_permlane32_swap_b32 %0, %1" : "+v"(pa1), "+v"(pb1));
      union { unsigned int u[4]; short8 v; } pk;
      pk.u[0] = pa0; pk.u[1] = pa1; pk.u[2] = pb0; pk.u[3] = pb1;
      const short8 pbv = pk.v;
      __builtin_amdgcn_s_setprio(1);
#pragma unroll
      for (int f = 0; f < 4; ++f) {
        const int rv = f * 16 + c16;
        const int cv = (4 * kk + g) ^ (rv & 7);
        const short8 vf =
            *reinterpret_cast<const short8*>((const char*)lv + rv * 128 + (cv << 4));
        o[f] = __builtin_amdgcn_mfma_f32_16x16x32_bf16(vf, pbv, o[f], 0, 0, 0);
      }
      lacc = __builtin_amdgcn_mfma_f32_16x16x32_bf16(ones, pbv, lacc, 0, 0, 0);
      __builtin_amdgcn_s_setprio(0);
    }
  };

  // prologue: V(0), K(0), K(1) (V first -> drain order at it0 works out)
  stageV(0);
  stageK(0);
  stageK(1);

#pragma unroll 2
  for (int it = 0; it < TT / 64; ++it) {
    if (it < TT / 64 - 1)
      asm volatile("s_waitcnt vmcnt(2)" ::: "memory");    // K(t),V(t) certified;
    else                                                  // K(t+1) stays in flight
      asm volatile("s_waitcnt vmcnt(0)" ::: "memory");
    __builtin_amdgcn_s_barrier();   // all waves: tile-t landed; compute(t-1) done
    if (it + 1 < TT / 64) stageV((it + 1) & 1);           // over V(t-1), consumed
    if (it + 2 < TT / 64) stageK((it + 2) % 3);           // over K(t-1), consumed
    compute((const unsigned short*)lsK[it % 3], (const unsigned short*)lsV[it & 1]);
  }

  // epilogue: normalize, vectorized 8B stores
  {
    const float inv = 1.0f / lacc[0];
    const size_t gm = (size_t)(b * TT + q0 + c16) * CC;
#pragma unroll
    for (int f = 0; f < 4; ++f) {
      ushortx4 ov;
#pragma unroll
      for (int r = 0; r < 4; ++r) ov[r] = f2bf(o[f][r] * inv);
      *reinterpret_cast<ushortx4*>(&Ob[gm + h * HD + f * 16 + 4 * g]) = ov;
    }
  }
}

extern "C" void kernel_launch(void* const* d_in, const int* in_sizes, int n_in,
                              void* d_out, int out_size, void* d_ws, size_t ws_size,
                              hipStream_t stream) {
  (void)in_sizes; (void)n_in; (void)out_size; (void)ws_size;
  const float* x  = (const float*)d_in[0];
  const float* Wk = (const float*)d_in[1];
  const float* bk = (const float*)d_in[2];
  const float* Wq = (const float*)d_in[3];
  const float* bq = (const float*)d_in[4];
  const float* Wv = (const float*)d_in[5];
  const float* bv = (const float*)d_in[6];
  const float* Wp = (const float*)d_in[7];
  const float* bp = (const float*)d_in[8];
  float* out = (float*)d_out;

  char* ws = (char*)d_ws;
  const size_t MB = 1u << 20;
  unsigned short* xb    = (unsigned short*)(ws);            // 8 MB [4096][1024]
  unsigned short* Wqkvb = (unsigned short*)(ws + 8 * MB);   // 6 MB [3072][1024] (q,k,v)
  unsigned short* Wpb   = (unsigned short*)(ws + 14 * MB);  // 2 MB
  unsigned short* QKVb  = (unsigned short*)(ws + 16 * MB);  // 24 MB [4096][3072] (V third unused)
  unsigned short* Vtb   = (unsigned short*)(ws + 40 * MB);  // 8 MB [32][64][2048] permuted
  unsigned short* Ab    = (unsigned short*)(ws + 48 * MB);  // 8 MB [4096][1024]

  cvt_fused<<<8192, 256, 0, stream>>>(x, Wq, Wk, Wv, Wp, xb, Wqkvb, Wpb);

  // fused QKV GEMM (256x192, 256 blocks = 1/CU, XCD-chunked); V third -> permuted Vt
  gemm_qkv<<<256, 512, 0, stream>>>(xb, Wqkvb, bq, bk, bv, QKVb, Vtb);

  // bh on blockIdx.x: all q-chunks of one bh share an XCD -> K/V L2 locality
  attn_fwd<<<dim3(2 * NH, TT / 64), 256, 0, stream>>>(QKVb, Vtb, Ab);

  gemm_proj<<<256, 256, 0, stream>>>(Ab, Wpb, bp, out);
}